// Round 1
// baseline (2061.614 us; speedup 1.0000x reference)
//
#include <hip/hip_runtime.h>

// ---------------- workspace layout (floats) ----------------
#define OFF_W1R   0
#define OFF_W2R   288
#define OFF_W3R   (288+18432)            // 18720
#define OFF_EWT   (18720+73728)          // 92448
#define OFF_CT    (92448+147456)         // 239904
#define OFF_CC    (239904+131072)        // 370976
#define OFF_DWT   (370976+1024)          // 372000
#define OFF_D1R   (372000+147456)        // 519456
#define OFF_D2R   (519456+73728)         // 593184
#define OFF_D3R   (593184+18432)         // 611616
#define WS_FLOATS (611616+288)           // 611904

// Repack all weights into lane-coalesced layouts:
//  w1r[tap][co32], w2r[(ci*9+tap)][co64], w3r[(ci*9+tap)][co128]
//  ewt[k][j] (enc_fc^T), ct[j][k] (codebook^T), cc[k]=||c_k||^2, dwt[k][j] (dec_fc^T)
//  d1r/d2r/d3r: conv-transpose effective weights (flip + in/out swap), [(ci*9+tap)][co]
__global__ void vq_prep(const float* __restrict__ conv1_w, const float* __restrict__ conv2_w,
                        const float* __restrict__ conv3_w, const float* __restrict__ enc_fc_w,
                        const float* __restrict__ codebook, const float* __restrict__ dec_fc_w,
                        const float* __restrict__ dct1_w, const float* __restrict__ dct2_w,
                        const float* __restrict__ dct3_w, float* __restrict__ ws) {
  int i = blockIdx.x * blockDim.x + threadIdx.x;
  if (i >= WS_FLOATS) return;
  if (i < OFF_W2R) {
    int tap = i >> 5, co = i & 31;
    ws[i] = conv1_w[co*9 + tap];
  } else if (i < OFF_W3R) {
    int l = i - OFF_W2R;
    int co = l & 63, r = l >> 6, tap = r % 9, ci = r / 9;
    ws[i] = conv2_w[(co*32 + ci)*9 + tap];
  } else if (i < OFF_EWT) {
    int l = i - OFF_W3R;
    int co = l & 127, r = l >> 7, tap = r % 9, ci = r / 9;
    ws[i] = conv3_w[(co*64 + ci)*9 + tap];
  } else if (i < OFF_CT) {
    int l = i - OFF_EWT;
    int j = l & 127, k = l >> 7;
    ws[i] = enc_fc_w[j*1152 + k];
  } else if (i < OFF_CC) {
    int l = i - OFF_CT;
    int k = l & 1023, j = l >> 10;
    ws[i] = codebook[k*128 + j];
  } else if (i < OFF_DWT) {
    int k = i - OFF_CC;
    float s = 0.f;
    for (int j = 0; j < 128; ++j) { float v = codebook[k*128+j]; s += v*v; }
    ws[i] = s;
  } else if (i < OFF_D1R) {
    int l = i - OFF_DWT;
    int j = l % 1152, k = l / 1152;
    ws[i] = dec_fc_w[j*128 + k];
  } else if (i < OFF_D2R) {
    int l = i - OFF_D1R;
    int co = l & 63, r = l >> 6, tap = r % 9, ci = r / 9;
    ws[i] = dct1_w[(ci*64 + co)*9 + (8 - tap)];
  } else if (i < OFF_D3R) {
    int l = i - OFF_D2R;
    int co = l & 31, r = l >> 5, tap = r % 9, ci = r / 9;
    ws[i] = dct2_w[(ci*32 + co)*9 + (8 - tap)];
  } else {
    int l = i - OFF_D3R;
    int tap = l % 9, ci = l / 9;
    ws[i] = dct3_w[ci*9 + (8 - tap)];
  }
}

// One block = one sample. 256 threads. Whole network in LDS.
__global__ __launch_bounds__(256, 2) void vq_main(
    const float* __restrict__ x,
    const float* __restrict__ b1, const float* __restrict__ b2, const float* __restrict__ b3,
    const float* __restrict__ enc_b, const float* __restrict__ codebook,
    const float* __restrict__ dec_b,
    const float* __restrict__ d1b, const float* __restrict__ d2b, const float* __restrict__ d3b,
    const float* __restrict__ ws, float* __restrict__ out)
{
  const int t = threadIdx.x;
  const int b = blockIdx.x;
  // R0: conv1-out padded [32][14][14] (6272), later D2-out padded (B')
  // R1: x padded [26][26] (676) / conv2-out padded [64][8][8] (4096) / conv3 partial
  //     scratch (4608) / D1-out padded [64][8][8] (C') / D2 partial scratch (3456)
  // R2: z[0:128], zq[128:256], zz@288-tree, argmin val[288:544] idx[544:800], fc partial[800:928]
  // R3: conv3-out [128*9] (1152) / dec-fc-out padded [128][5][5] (3200) / D1 partial scratch (1728)
  __shared__ float R0[6272];
  __shared__ float R1[4608];
  __shared__ float R2[1024];
  __shared__ float R3[3200];

  for (int i = t; i < 6272; i += 256) R0[i] = 0.f;
  for (int i = t; i < 676;  i += 256) R1[i] = 0.f;
  __syncthreads();

  // ---- load x into padded 26x26 ----
  const float* xb = x + (size_t)b * 576;
  for (int i = t; i < 576; i += 256) {
    int y = i / 24, xx = i - y * 24;
    R1[(y+1)*26 + (xx+1)] = xb[i];
  }
  __syncthreads();

  // ---- conv1 (1->32, 24x24) + relu + pool -> R0 [32][14][14] padded ----
  {
    int co = t & 31, g = t >> 5, gy = g >> 1, gx = g & 1;
    float w[9];
    #pragma unroll
    for (int k = 0; k < 9; ++k) w[k] = ws[OFF_W1R + k*32 + co];
    float bias = b1[co];
    #pragma unroll
    for (int pr = 0; pr < 3; ++pr) {
      int Y = gy*6 + pr*2;
      float a0[12], a1[12];
      #pragma unroll
      for (int i = 0; i < 12; ++i) { a0[i] = 0.f; a1[i] = 0.f; }
      #pragma unroll
      for (int wy = 0; wy < 4; ++wy) {
        const float2* rp = (const float2*)&R1[(Y+wy)*26 + gx*12];
        float r[14];
        #pragma unroll
        for (int k = 0; k < 7; ++k) { float2 p = rp[k]; r[2*k] = p.x; r[2*k+1] = p.y; }
        if (wy < 3) {
          #pragma unroll
          for (int xx = 0; xx < 12; ++xx)
            #pragma unroll
            for (int dx = 0; dx < 3; ++dx) a0[xx] += r[xx+dx] * w[wy*3+dx];
        }
        if (wy >= 1) {
          #pragma unroll
          for (int xx = 0; xx < 12; ++xx)
            #pragma unroll
            for (int dx = 0; dx < 3; ++dx) a1[xx] += r[xx+dx] * w[(wy-1)*3+dx];
        }
      }
      #pragma unroll
      for (int pc = 0; pc < 6; ++pc) {
        float m = fmaxf(fmaxf(a0[2*pc], a0[2*pc+1]), fmaxf(a1[2*pc], a1[2*pc+1]));
        float v = m + bias; v = v > 0.f ? v : 0.f;
        R0[co*196 + (1+gy*3+pr)*14 + (1+gx*6+pc)] = v;
      }
    }
  }
  __syncthreads();
  for (int i = t; i < 4096; i += 256) R1[i] = 0.f;   // zero padded conv2-out
  __syncthreads();

  // ---- conv2 (32->64, 12x12) + relu + pool -> R1 [64][8][8] padded ----
  {
    int co = t & 63, g = t >> 6, gy = g >> 1, gx = g & 1;
    float acc[36];
    #pragma unroll
    for (int i = 0; i < 36; ++i) acc[i] = 0.f;
    const float* wbase = ws + OFF_W2R + co;
    for (int ci = 0; ci < 32; ++ci) {
      float w[9];
      #pragma unroll
      for (int k = 0; k < 9; ++k) w[k] = wbase[(ci*9+k)*64];
      const float* inb = &R0[ci*196 + gy*6*14 + gx*6];
      #pragma unroll
      for (int wy = 0; wy < 8; ++wy) {
        const float2* rp = (const float2*)(inb + wy*14);
        float r[8];
        #pragma unroll
        for (int k = 0; k < 4; ++k) { float2 p = rp[k]; r[2*k] = p.x; r[2*k+1] = p.y; }
        #pragma unroll
        for (int y = 0; y < 6; ++y) {
          int dy = wy - y;
          if (dy >= 0 && dy < 3) {
            #pragma unroll
            for (int xx = 0; xx < 6; ++xx)
              #pragma unroll
              for (int dx = 0; dx < 3; ++dx) acc[y*6+xx] += r[xx+dx] * w[dy*3+dx];
          }
        }
      }
    }
    float bias = b2[co];
    #pragma unroll
    for (int pr = 0; pr < 3; ++pr)
      #pragma unroll
      for (int pc = 0; pc < 3; ++pc) {
        float m = fmaxf(fmaxf(acc[(2*pr)*6+2*pc], acc[(2*pr)*6+2*pc+1]),
                        fmaxf(acc[(2*pr+1)*6+2*pc], acc[(2*pr+1)*6+2*pc+1]));
        float v = m + bias; v = v > 0.f ? v : 0.f;
        R1[co*64 + (1+gy*3+pr)*8 + (1+gx*3+pc)] = v;
      }
  }
  __syncthreads();

  // ---- conv3 (64->128, 6x6) + relu + pool -> R3 [128*9] ----
  {
    int co = t & 127, g = t >> 7;
    float acc[36];
    #pragma unroll
    for (int i = 0; i < 36; ++i) acc[i] = 0.f;
    const float* wbase = ws + OFF_W3R + co;
    for (int ci = g*32; ci < g*32+32; ++ci) {
      float w[9];
      #pragma unroll
      for (int k = 0; k < 9; ++k) w[k] = wbase[(ci*9+k)*128];
      const float* inb = &R1[ci*64];
      #pragma unroll
      for (int wy = 0; wy < 8; ++wy) {
        const float2* rp = (const float2*)(inb + wy*8);
        float r[8];
        #pragma unroll
        for (int k = 0; k < 4; ++k) { float2 p = rp[k]; r[2*k] = p.x; r[2*k+1] = p.y; }
        #pragma unroll
        for (int y = 0; y < 6; ++y) {
          int dy = wy - y;
          if (dy >= 0 && dy < 3) {
            #pragma unroll
            for (int xx = 0; xx < 6; ++xx)
              #pragma unroll
              for (int dx = 0; dx < 3; ++dx) acc[y*6+xx] += r[xx+dx] * w[dy*3+dx];
          }
        }
      }
    }
    __syncthreads();                       // all conv3 input reads done
    if (g == 1) {
      #pragma unroll
      for (int i = 0; i < 36; ++i) R1[co*36 + i] = acc[i];
    }
    __syncthreads();
    if (g == 0) {
      float bias = b3[co];
      #pragma unroll
      for (int i = 0; i < 36; ++i) acc[i] += R1[co*36 + i];
      #pragma unroll
      for (int pr = 0; pr < 3; ++pr)
        #pragma unroll
        for (int pc = 0; pc < 3; ++pc) {
          float m = fmaxf(fmaxf(acc[(2*pr)*6+2*pc], acc[(2*pr)*6+2*pc+1]),
                          fmaxf(acc[(2*pr+1)*6+2*pc], acc[(2*pr+1)*6+2*pc+1]));
          float v = m + bias; v = v > 0.f ? v : 0.f;
          R3[co*9 + pr*3 + pc] = v;
        }
    }
  }
  __syncthreads();

  // ---- enc_fc (1152->128) ----
  float zval = 0.f;
  {
    int j = t & 127, g = t >> 7;
    float acc = 0.f;
    const float* wb = ws + OFF_EWT + j;
    const float2* Dp = (const float2*)R3;
    for (int k2 = g*288; k2 < g*288+288; ++k2) {
      float2 dv = Dp[k2];
      acc += wb[(2*k2)*128] * dv.x + wb[(2*k2+1)*128] * dv.y;
    }
    if (g == 1) R2[800 + j] = acc;
    __syncthreads();
    if (g == 0) {
      zval = acc + R2[800 + j] + enc_b[j];
      R2[j] = zval;
    }
  }
  __syncthreads();

  // ---- zz = ||z||^2 tree; also zero R1 (future D1-out) and R3 (future dec-fc-out) ----
  if (t < 128) R2[288 + t] = zval * zval;
  for (int i = t; i < 4608; i += 256) R1[i] = 0.f;
  for (int i = t; i < 3200; i += 256) R3[i] = 0.f;
  __syncthreads();
  for (int s = 64; s >= 1; s >>= 1) {
    if (t < s) R2[288 + t] += R2[288 + t + s];
    __syncthreads();
  }

  // ---- quantize: d2 = zz - 2 z.c + cc, first-index argmin over 1024 ----
  float bestv; int besti;
  {
    float zz = R2[288];
    const float* ct = ws + OFF_CT;
    const float* cc = ws + OFF_CC;
    float dot0 = 0.f, dot1 = 0.f, dot2 = 0.f, dot3 = 0.f;
    for (int j = 0; j < 128; ++j) {
      float zv = R2[j];
      const float* cp = ct + j*1024 + t;
      dot0 += zv * cp[0];   dot1 += zv * cp[256];
      dot2 += zv * cp[512]; dot3 += zv * cp[768];
    }
    bestv = (zz - 2.f*dot0) + cc[t];       besti = t;
    float v1 = (zz - 2.f*dot1) + cc[256+t]; if (v1 < bestv) { bestv = v1; besti = 256+t; }
    float v2 = (zz - 2.f*dot2) + cc[512+t]; if (v2 < bestv) { bestv = v2; besti = 512+t; }
    float v3 = (zz - 2.f*dot3) + cc[768+t]; if (v3 < bestv) { bestv = v3; besti = 768+t; }
  }
  __syncthreads();
  R2[288 + t] = bestv; R2[544 + t] = (float)besti;
  __syncthreads();
  for (int s = 128; s >= 1; s >>= 1) {
    if (t < s) {
      float v2 = R2[288+t+s], i2 = R2[544+t+s];
      float v1 = R2[288+t],   i1 = R2[544+t];
      if (v2 < v1 || (v2 == v1 && i2 < i1)) { R2[288+t] = v2; R2[544+t] = i2; }
    }
    __syncthreads();
  }
  {
    int idx = (int)R2[544];
    if (t < 128) R2[128 + t] = codebook[idx*128 + t];
  }
  __syncthreads();

  // ---- dec_fc (128->1152) -> R3 padded [128][5][5] ----
  {
    const float2* zqp = (const float2*)&R2[128];
    const float* wb = ws + OFF_DWT;
    #pragma unroll
    for (int q = 0; q < 5; ++q) {
      int j = t + q*256;
      if (j < 1152) {
        float acc = dec_b[j];
        const float* wj = wb + j;
        for (int k2 = 0; k2 < 64; ++k2) {
          float2 zv = zqp[k2];
          acc += wj[(2*k2)*1152] * zv.x + wj[(2*k2+1)*1152] * zv.y;
        }
        int co = j / 9, r = j - co*9, yy = r / 3, xx = r - yy*3;
        R3[co*25 + (yy+1)*5 + (xx+1)] = acc;
      }
    }
  }
  __syncthreads();

  // ---- D1: convT eff (128->64, 3x3) + relu + upsample -> R1 [64][8][8] padded ----
  {
    int co = t & 63, g = t >> 6;
    float a9[9];
    #pragma unroll
    for (int i = 0; i < 9; ++i) a9[i] = 0.f;
    const float* wbase = ws + OFF_D1R + co;
    for (int ci = g*32; ci < g*32+32; ++ci) {
      float w[9];
      #pragma unroll
      for (int k = 0; k < 9; ++k) w[k] = wbase[(ci*9+k)*64];
      const float* inb = &R3[ci*25];
      #pragma unroll
      for (int wy = 0; wy < 5; ++wy) {
        float r[5];
        #pragma unroll
        for (int c = 0; c < 5; ++c) r[c] = inb[wy*5 + c];
        #pragma unroll
        for (int y = 0; y < 3; ++y) {
          int dy = wy - y;
          if (dy >= 0 && dy < 3) {
            #pragma unroll
            for (int xx = 0; xx < 3; ++xx)
              #pragma unroll
              for (int dx = 0; dx < 3; ++dx) a9[y*3+xx] += r[xx+dx] * w[dy*3+dx];
          }
        }
      }
    }
    __syncthreads();                        // all R3 (F) reads done
    if (g > 0) {
      #pragma unroll
      for (int i = 0; i < 9; ++i) R3[((g-1)*64 + co)*9 + i] = a9[i];
    }
    __syncthreads();
    if (g == 0) {
      float bias = d1b[co];
      #pragma unroll
      for (int i = 0; i < 9; ++i)
        a9[i] += R3[co*9 + i] + R3[(64+co)*9 + i] + R3[(128+co)*9 + i];
      #pragma unroll
      for (int yy = 0; yy < 3; ++yy)
        #pragma unroll
        for (int xx = 0; xx < 3; ++xx) {
          float v = a9[yy*3+xx] + bias; v = v > 0.f ? v : 0.f;
          int r0 = co*64 + (1+2*yy)*8 + (1+2*xx);
          R1[r0] = v; R1[r0+1] = v; R1[r0+8] = v; R1[r0+9] = v;
        }
    }
  }
  __syncthreads();

  // ---- D2: convT eff (64->32, 6x6) + relu + upsample -> R0 [32][14][14] padded ----
  {
    int co = t & 31, gci = (t >> 5) & 3, gx = t >> 7;
    float a18[18];
    #pragma unroll
    for (int i = 0; i < 18; ++i) a18[i] = 0.f;
    const float* wbase = ws + OFF_D2R + co;
    for (int ci = gci*16; ci < gci*16+16; ++ci) {
      float w[9];
      #pragma unroll
      for (int k = 0; k < 9; ++k) w[k] = wbase[(ci*9+k)*32];
      const float* inb = &R1[ci*64 + gx*3];
      #pragma unroll
      for (int wy = 0; wy < 8; ++wy) {
        float r[5];
        #pragma unroll
        for (int c = 0; c < 5; ++c) r[c] = inb[wy*8 + c];
        #pragma unroll
        for (int y = 0; y < 6; ++y) {
          int dy = wy - y;
          if (dy >= 0 && dy < 3) {
            #pragma unroll
            for (int xx = 0; xx < 3; ++xx)
              #pragma unroll
              for (int dx = 0; dx < 3; ++dx) a18[y*3+xx] += r[xx+dx] * w[dy*3+dx];
          }
        }
      }
    }
    __syncthreads();                        // all R1 (C') reads done
    if (gci > 0) {
      #pragma unroll
      for (int i = 0; i < 18; ++i) R1[((gci-1)*64 + gx*32 + co)*18 + i] = a18[i];
    }
    __syncthreads();
    if (gci == 0) {
      float bias = d2b[co];
      #pragma unroll
      for (int i = 0; i < 18; ++i)
        a18[i] += R1[(gx*32+co)*18 + i] + R1[(64+gx*32+co)*18 + i] + R1[(128+gx*32+co)*18 + i];
      #pragma unroll
      for (int yy = 0; yy < 6; ++yy)
        #pragma unroll
        for (int xx = 0; xx < 3; ++xx) {
          float v = a18[yy*3+xx] + bias; v = v > 0.f ? v : 0.f;
          int gxx = gx*3 + xx;
          int r0 = co*196 + (1+2*yy)*14 + (1+2*gxx);
          R0[r0] = v; R0[r0+1] = v; R0[r0+14] = v; R0[r0+15] = v;
        }
    }
  }
  __syncthreads();

  // ---- D3: convT eff (32->1, 12x12) + relu + upsample -> out [24][24] ----
  if (t < 144) {
    int yy = t / 12, xx = t - yy*12;
    const float* w3 = ws + OFF_D3R;
    float acc = d3b[0];
    for (int ci = 0; ci < 32; ++ci) {
      const float* inb = &R0[ci*196 + yy*14 + xx];
      #pragma unroll
      for (int dy = 0; dy < 3; ++dy)
        #pragma unroll
        for (int dx = 0; dx < 3; ++dx)
          acc += inb[dy*14 + dx] * w3[ci*9 + dy*3 + dx];
    }
    float v = acc > 0.f ? acc : 0.f;
    float* ob = out + (size_t)b * 576;
    int o0 = (2*yy)*24 + 2*xx;
    ob[o0] = v; ob[o0+1] = v; ob[o0+24] = v; ob[o0+25] = v;
  }
}

extern "C" void kernel_launch(void* const* d_in, const int* in_sizes, int n_in,
                              void* d_out, int out_size, void* d_ws, size_t ws_size,
                              hipStream_t stream) {
  const float* x   = (const float*)d_in[0];
  const float* c1w = (const float*)d_in[1];
  const float* c1b = (const float*)d_in[2];
  const float* c2w = (const float*)d_in[3];
  const float* c2b = (const float*)d_in[4];
  const float* c3w = (const float*)d_in[5];
  const float* c3b = (const float*)d_in[6];
  const float* efw = (const float*)d_in[7];
  const float* efb = (const float*)d_in[8];
  const float* cb  = (const float*)d_in[9];
  const float* dfw = (const float*)d_in[10];
  const float* dfb = (const float*)d_in[11];
  const float* dw1 = (const float*)d_in[12];
  const float* db1 = (const float*)d_in[13];
  const float* dw2 = (const float*)d_in[14];
  const float* db2 = (const float*)d_in[15];
  const float* dw3 = (const float*)d_in[16];
  const float* db3 = (const float*)d_in[17];
  float* ws = (float*)d_ws;
  float* outp = (float*)d_out;
  int B = in_sizes[0] / 576;

  vq_prep<<<(WS_FLOATS + 255) / 256, 256, 0, stream>>>(c1w, c2w, c3w, efw, cb, dfw, dw1, dw2, dw3, ws);
  vq_main<<<B, 256, 0, stream>>>(x, c1b, c2b, c3b, efb, cb, dfb, db1, db2, db3, ws, outp);
}

// Round 2
// 1860.779 us; speedup vs baseline: 1.1079x; 1.1079x over previous
//
#include <hip/hip_runtime.h>

// ---------------- workspace layout (floats) ----------------
#define OFF_W1R   0
#define OFF_W2R   288
#define OFF_W3R   (288+18432)            // 18720
#define OFF_EWT   (18720+73728)          // 92448   ewt[k][128j]
#define OFF_CT    (92448+147456)         // 239904  ct[k][1024cw]
#define OFF_CC    (239904+131072)        // 370976  cc[1024]
#define OFF_DWT   (370976+1024)          // 372000  dwt[k][1152j]
#define OFF_D1R   (372000+147456)        // 519456
#define OFF_D2R   (519456+73728)         // 593184
#define OFF_D3R   (593184+18432)         // 611616
#define WS_WEIGHTS (611616+288)          // 611904
#define OFF_Z     WS_WEIGHTS             // z [8192][128]
#define OFF_IDS   (OFF_Z + 8192*128)     // idx [8192] (int)

__global__ void vq_prep(const float* __restrict__ conv1_w, const float* __restrict__ conv2_w,
                        const float* __restrict__ conv3_w, const float* __restrict__ enc_fc_w,
                        const float* __restrict__ codebook, const float* __restrict__ dec_fc_w,
                        const float* __restrict__ dct1_w, const float* __restrict__ dct2_w,
                        const float* __restrict__ dct3_w, float* __restrict__ ws) {
  int i = blockIdx.x * blockDim.x + threadIdx.x;
  if (i >= WS_WEIGHTS) return;
  if (i < OFF_W2R) {
    int tap = i >> 5, co = i & 31;
    ws[i] = conv1_w[co*9 + tap];
  } else if (i < OFF_W3R) {
    int l = i - OFF_W2R;
    int co = l & 63, r = l >> 6, tap = r % 9, ci = r / 9;
    ws[i] = conv2_w[(co*32 + ci)*9 + tap];
  } else if (i < OFF_EWT) {
    int l = i - OFF_W3R;
    int co = l & 127, r = l >> 7, tap = r % 9, ci = r / 9;
    ws[i] = conv3_w[(co*64 + ci)*9 + tap];
  } else if (i < OFF_CT) {
    int l = i - OFF_EWT;
    int j = l & 127, k = l >> 7;
    ws[i] = enc_fc_w[j*1152 + k];
  } else if (i < OFF_CC) {
    int l = i - OFF_CT;
    int k = l & 1023, j = l >> 10;
    ws[i] = codebook[k*128 + j];
  } else if (i < OFF_DWT) {
    int k = i - OFF_CC;
    float s = 0.f;
    for (int j = 0; j < 128; ++j) { float v = codebook[k*128+j]; s += v*v; }
    ws[i] = s;
  } else if (i < OFF_D1R) {
    int l = i - OFF_DWT;
    int j = l % 1152, k = l / 1152;
    ws[i] = dec_fc_w[j*128 + k];
  } else if (i < OFF_D2R) {
    int l = i - OFF_D1R;
    int co = l & 63, r = l >> 6, tap = r % 9, ci = r / 9;
    ws[i] = dct1_w[(ci*64 + co)*9 + (8 - tap)];
  } else if (i < OFF_D3R) {
    int l = i - OFF_D2R;
    int co = l & 31, r = l >> 5, tap = r % 9, ci = r / 9;
    ws[i] = dct2_w[(ci*32 + co)*9 + (8 - tap)];
  } else {
    int l = i - OFF_D3R;
    int tap = l % 9, ci = l / 9;
    ws[i] = dct3_w[ci*9 + (8 - tap)];
  }
}

// ---------------- encoder: 2 samples per block ----------------
// R0: conv1-out [32 ch @ stride 146][12r*12c], also conv3 partials [128 @ 37]
// R1: x-tile [24][26] colpad / conv2-out [64 @ 38][6r*6c] / enc_fc partials
// HB: pooled conv3 out [2][1152]
__global__ __launch_bounds__(256, 4) void vq_enc(
    const float* __restrict__ x,
    const float* __restrict__ b1, const float* __restrict__ b2, const float* __restrict__ b3,
    const float* __restrict__ encb, const float* __restrict__ ws, float* __restrict__ zout)
{
  __shared__ float R0[4736];
  __shared__ float R1[2432];
  __shared__ float HB[2304];
  const int t = threadIdx.x;
  const int s0 = blockIdx.x * 2;

  for (int s = 0; s < 2; ++s) {
    __syncthreads();
    // ---- stage x -> R1 [24][26] with zero col-pads ----
    const float* xb = x + (size_t)(s0 + s) * 576;
    for (int i = t; i < 624; i += 256) {
      int row = i / 26, col = i - row * 26;
      R1[i] = (col >= 1 && col <= 24) ? xb[row*24 + col - 1] : 0.f;
    }
    __syncthreads();

    // ---- conv1 (1->32) + relu + pool -> R0 ----
    {
      int co = t & 31, g = t >> 5, gy = g >> 1, gx = g & 1;
      float w[9];
      #pragma unroll
      for (int k = 0; k < 9; ++k) w[k] = ws[OFF_W1R + k*32 + co];
      float bias = b1[co];
      #pragma unroll
      for (int pr = 0; pr < 3; ++pr) {
        int Y = gy*6 + pr*2;     // raw rows Y, Y+1; window rows Y-1..Y+2
        float a0[12], a1[12];
        #pragma unroll
        for (int i = 0; i < 12; ++i) { a0[i] = 0.f; a1[i] = 0.f; }
        #pragma unroll
        for (int wy = 0; wy < 4; ++wy) {
          int ry = Y - 1 + wy;
          if (ry < 0 || ry > 23) continue;       // wave-uniform (gy uniform)
          const float2* rp = (const float2*)&R1[ry*26 + gx*12];
          float r[14];
          #pragma unroll
          for (int k = 0; k < 7; ++k) { float2 p = rp[k]; r[2*k] = p.x; r[2*k+1] = p.y; }
          if (wy < 3) {
            #pragma unroll
            for (int xx = 0; xx < 12; ++xx)
              #pragma unroll
              for (int dx = 0; dx < 3; ++dx) a0[xx] += r[xx+dx] * w[wy*3+dx];
          }
          if (wy >= 1) {
            #pragma unroll
            for (int xx = 0; xx < 12; ++xx)
              #pragma unroll
              for (int dx = 0; dx < 3; ++dx) a1[xx] += r[xx+dx] * w[(wy-1)*3+dx];
          }
        }
        #pragma unroll
        for (int pc = 0; pc < 6; ++pc) {
          float m = fmaxf(fmaxf(a0[2*pc], a0[2*pc+1]), fmaxf(a1[2*pc], a1[2*pc+1]));
          float v = m + bias; v = v > 0.f ? v : 0.f;
          R0[co*146 + (gy*3+pr)*12 + gx*6 + pc] = v;
        }
      }
    }
    __syncthreads();

    // ---- conv2 (32->64) + relu + pool -> R1 [64 @38][6][6] ----
    {
      int co = t & 63, g = t >> 6, gy = g >> 1, gx = g & 1;  // g wave-uniform
      float acc[36];
      #pragma unroll
      for (int i = 0; i < 36; ++i) acc[i] = 0.f;
      const float* wbase = ws + OFF_W2R + co;
      for (int ci = 0; ci < 32; ++ci) {
        float w[9];
        #pragma unroll
        for (int k = 0; k < 9; ++k) w[k] = wbase[(ci*9+k)*64];
        const float* base = &R0[ci*146];
        #pragma unroll
        for (int wy = 0; wy < 8; ++wy) {
          int ry = gy*6 - 1 + wy;
          if (ry < 0 || ry > 11) continue;       // wave-uniform
          const float* row = base + ry*12;
          float r[8];
          if (gx == 0) {                          // wave-uniform
            r[0] = 0.f;
            float2 p0 = *(const float2*)(row);
            float2 p1 = *(const float2*)(row+2);
            float2 p2 = *(const float2*)(row+4);
            r[1]=p0.x; r[2]=p0.y; r[3]=p1.x; r[4]=p1.y; r[5]=p2.x; r[6]=p2.y; r[7]=row[6];
          } else {
            r[0] = row[5];
            float2 p0 = *(const float2*)(row+6);
            float2 p1 = *(const float2*)(row+8);
            float2 p2 = *(const float2*)(row+10);
            r[1]=p0.x; r[2]=p0.y; r[3]=p1.x; r[4]=p1.y; r[5]=p2.x; r[6]=p2.y; r[7]=0.f;
          }
          #pragma unroll
          for (int y = 0; y < 6; ++y) {
            int d = wy - y;
            if (d >= 0 && d < 3) {
              #pragma unroll
              for (int xx = 0; xx < 6; ++xx)
                #pragma unroll
                for (int dx = 0; dx < 3; ++dx) acc[y*6+xx] += r[xx+dx] * w[d*3+dx];
            }
          }
        }
      }
      float bias = b2[co];
      #pragma unroll
      for (int pr = 0; pr < 3; ++pr)
        #pragma unroll
        for (int pc = 0; pc < 3; ++pc) {
          float m = fmaxf(fmaxf(acc[(2*pr)*6+2*pc], acc[(2*pr)*6+2*pc+1]),
                          fmaxf(acc[(2*pr+1)*6+2*pc], acc[(2*pr+1)*6+2*pc+1]));
          float v = m + bias; v = v > 0.f ? v : 0.f;
          R1[co*38 + (gy*3+pr)*6 + (gx*3+pc)] = v;
        }
    }
    __syncthreads();

    // ---- conv3 (64->128) + relu + pool -> HB[s][1152] ----
    {
      int co = t & 127, g = t >> 7;
      float acc[36];
      #pragma unroll
      for (int i = 0; i < 36; ++i) acc[i] = 0.f;
      const float* wbase = ws + OFF_W3R + co;
      for (int ci = g*32; ci < g*32+32; ++ci) {
        float w[9];
        #pragma unroll
        for (int k = 0; k < 9; ++k) w[k] = wbase[(ci*9+k)*128];
        const float* base = &R1[ci*38];
        #pragma unroll
        for (int ry = 0; ry < 6; ++ry) {
          float r[8];
          r[0] = 0.f; r[7] = 0.f;
          float2 p0 = *(const float2*)(base + ry*6);
          float2 p1 = *(const float2*)(base + ry*6 + 2);
          float2 p2 = *(const float2*)(base + ry*6 + 4);
          r[1]=p0.x; r[2]=p0.y; r[3]=p1.x; r[4]=p1.y; r[5]=p2.x; r[6]=p2.y;
          #pragma unroll
          for (int y = 0; y < 6; ++y) {
            int d = ry - y + 1;
            if (d >= 0 && d < 3) {
              #pragma unroll
              for (int xx = 0; xx < 6; ++xx)
                #pragma unroll
                for (int dx = 0; dx < 3; ++dx) acc[y*6+xx] += r[xx+dx] * w[d*3+dx];
            }
          }
        }
      }
      __syncthreads();                 // all R1 reads done
      if (g) {
        #pragma unroll
        for (int i = 0; i < 36; ++i) R0[co*37 + i] = acc[i];
      }
      __syncthreads();
      if (!g) {
        float bias = b3[co];
        #pragma unroll
        for (int i = 0; i < 36; ++i) acc[i] += R0[co*37 + i];
        #pragma unroll
        for (int pr = 0; pr < 3; ++pr)
          #pragma unroll
          for (int pc = 0; pc < 3; ++pc) {
            float m = fmaxf(fmaxf(acc[(2*pr)*6+2*pc], acc[(2*pr)*6+2*pc+1]),
                            fmaxf(acc[(2*pr+1)*6+2*pc], acc[(2*pr+1)*6+2*pc+1]));
            float v = m + bias; v = v > 0.f ? v : 0.f;
            HB[s*1152 + co*9 + pr*3 + pc] = v;
          }
      }
    }
  }
  __syncthreads();

  // ---- enc_fc (1152->128), both samples ----
  {
    int j = t & 127, g = t >> 7;
    float a0 = 0.f, a1 = 0.f;
    const float* wb = ws + OFF_EWT + j;
    #pragma unroll 4
    for (int k = g*576; k < g*576 + 576; ++k) {
      float wv = wb[k*128];
      a0 += wv * HB[k];
      a1 += wv * HB[1152 + k];
    }
    if (g) { R1[j] = a0; R1[128 + j] = a1; }
    __syncthreads();
    if (!g) {
      float bias = encb[j];
      zout[(size_t)s0*128 + j]       = a0 + R1[j]       + bias;
      zout[(size_t)(s0+1)*128 + j]   = a1 + R1[128 + j] + bias;
    }
  }
}

// ---------------- argmin: 16 samples per block ----------------
__global__ __launch_bounds__(256, 4) void vq_argmin(
    const float* __restrict__ z, const float* __restrict__ ws, int* __restrict__ ids)
{
  __shared__ float ZT[128*18];   // [k][16s pad 18]
  const int t = threadIdx.x;
  const int sb = blockIdx.x * 16;
  {
    int s = t >> 4, k0 = (t & 15) * 8;
    const float4* zr = (const float4*)(z + (size_t)(sb + s)*128 + k0);
    float4 p0 = zr[0], p1 = zr[1];
    ZT[(k0+0)*18 + s] = p0.x; ZT[(k0+1)*18 + s] = p0.y;
    ZT[(k0+2)*18 + s] = p0.z; ZT[(k0+3)*18 + s] = p0.w;
    ZT[(k0+4)*18 + s] = p1.x; ZT[(k0+5)*18 + s] = p1.y;
    ZT[(k0+6)*18 + s] = p1.z; ZT[(k0+7)*18 + s] = p1.w;
  }
  __syncthreads();
  int cg = t & 31, sg = t >> 5;
  int s0 = sg * 2;
  float bestv0 = 3.4e38f, bestv1 = 3.4e38f;
  int besti0 = 0, besti1 = 0;
  for (int p = 0; p < 8; ++p) {
    int cw0 = p*128 + cg*4;
    float acc[2][4];
    #pragma unroll
    for (int i = 0; i < 2; ++i)
      #pragma unroll
      for (int jj = 0; jj < 4; ++jj) acc[i][jj] = 0.f;
    #pragma unroll 4
    for (int k = 0; k < 128; ++k) {
      float4 cv = *(const float4*)(ws + OFF_CT + k*1024 + cw0);
      float2 av = *(const float2*)(&ZT[k*18 + s0]);
      acc[0][0] += av.x*cv.x; acc[0][1] += av.x*cv.y; acc[0][2] += av.x*cv.z; acc[0][3] += av.x*cv.w;
      acc[1][0] += av.y*cv.x; acc[1][1] += av.y*cv.y; acc[1][2] += av.y*cv.z; acc[1][3] += av.y*cv.w;
    }
    float4 ccv = *(const float4*)(ws + OFF_CC + cw0);
    float cc4[4] = {ccv.x, ccv.y, ccv.z, ccv.w};
    #pragma unroll
    for (int jj = 0; jj < 4; ++jj) {
      float v0 = cc4[jj] - 2.f*acc[0][jj];
      float v1 = cc4[jj] - 2.f*acc[1][jj];
      if (v0 < bestv0) { bestv0 = v0; besti0 = cw0 + jj; }
      if (v1 < bestv1) { bestv1 = v1; besti1 = cw0 + jj; }
    }
  }
  // reduce across the 32 cg lanes (xor stays within the sg half-wave)
  #pragma unroll
  for (int off = 16; off >= 1; off >>= 1) {
    float v0 = __shfl_xor(bestv0, off); int i0 = __shfl_xor(besti0, off);
    float v1 = __shfl_xor(bestv1, off); int i1 = __shfl_xor(besti1, off);
    if (v0 < bestv0 || (v0 == bestv0 && i0 < besti0)) { bestv0 = v0; besti0 = i0; }
    if (v1 < bestv1 || (v1 == bestv1 && i1 < besti1)) { bestv1 = v1; besti1 = i1; }
  }
  if (cg == 0) {
    ids[sb + s0]     = besti0;
    ids[sb + s0 + 1] = besti1;
  }
}

// ---------------- decoder: 2 samples per block ----------------
// DB: d [2][1152] (per-sample slice reused for D2 partials)
// R1: D1-out [64 @38][6][6]   R0: D1 partials / D2-out [32 @146][12][12]
__global__ __launch_bounds__(256, 4) void vq_dec(
    const float* __restrict__ codebook, const float* __restrict__ decb,
    const float* __restrict__ d1b, const float* __restrict__ d2b, const float* __restrict__ d3b,
    const float* __restrict__ ws, const int* __restrict__ ids, float* __restrict__ out)
{
  __shared__ float DB[2304];
  __shared__ float R1[2432];
  __shared__ float R0[4736];
  __shared__ float ZQ[256];
  __shared__ int IDX[2];
  const int t = threadIdx.x;
  const int s0 = blockIdx.x * 2;

  if (t < 2) IDX[t] = ids[s0 + t];
  __syncthreads();
  { int s = t >> 7, j = t & 127; ZQ[s*128 + j] = codebook[(size_t)IDX[s]*128 + j]; }
  __syncthreads();

  // ---- dec_fc (128->1152), both samples ----
  #pragma unroll
  for (int p = 0; p < 5; ++p) {
    int j = t + p*256;
    if (j < 1152) {
      float a0 = decb[j], a1 = a0;
      const float* wb = ws + OFF_DWT + j;
      #pragma unroll 4
      for (int k = 0; k < 128; ++k) {
        float wv = wb[k*1152];
        a0 += wv * ZQ[k];
        a1 += wv * ZQ[128 + k];
      }
      DB[j] = a0; DB[1152 + j] = a1;
    }
  }

  for (int s = 0; s < 2; ++s) {
    __syncthreads();
    const float* F = &DB[s*1152];
    float* PS = &DB[s*1152];          // same slice reused for D2 partials (dead after D1)

    // ---- D1 (128->64, 3x3) + relu + upsample -> R1 ----
    {
      int co = t & 63, g = t >> 6;    // wave-uniform g
      float a9[9];
      #pragma unroll
      for (int i = 0; i < 9; ++i) a9[i] = 0.f;
      const float* wbase = ws + OFF_D1R + co;
      for (int ci = g*32; ci < g*32+32; ++ci) {
        float w[9];
        #pragma unroll
        for (int k = 0; k < 9; ++k) w[k] = wbase[(ci*9+k)*64];
        const float* fin = F + ci*9;
        #pragma unroll
        for (int ry = 0; ry < 3; ++ry) {
          float r[5];
          r[0] = 0.f; r[4] = 0.f;
          r[1] = fin[ry*3]; r[2] = fin[ry*3+1]; r[3] = fin[ry*3+2];
          #pragma unroll
          for (int y = 0; y < 3; ++y) {
            int d = ry - y + 1;
            if (d >= 0 && d < 3) {
              #pragma unroll
              for (int xx = 0; xx < 3; ++xx)
                #pragma unroll
                for (int dx = 0; dx < 3; ++dx) a9[y*3+xx] += r[xx+dx] * w[d*3+dx];
            }
          }
        }
      }
      __syncthreads();                 // F reads done
      if (g) {
        #pragma unroll
        for (int i = 0; i < 9; ++i) R0[((g-1)*64 + co)*9 + i] = a9[i];
      }
      __syncthreads();
      if (!g) {
        float bias = d1b[co];
        #pragma unroll
        for (int i = 0; i < 9; ++i)
          a9[i] += R0[co*9 + i] + R0[(64+co)*9 + i] + R0[(128+co)*9 + i];
        #pragma unroll
        for (int yy = 0; yy < 3; ++yy)
          #pragma unroll
          for (int xx = 0; xx < 3; ++xx) {
            float v = a9[yy*3+xx] + bias; v = v > 0.f ? v : 0.f;
            int base = co*38 + (2*yy)*6 + 2*xx;
            R1[base] = v; R1[base+1] = v; R1[base+6] = v; R1[base+7] = v;
          }
      }
    }
    __syncthreads();

    // ---- D2 (64->32, 6x6) + relu + upsample -> R0 ----
    {
      int co = t & 31, h = (t >> 5) & 1, g = t >> 6;   // g (quadrant) wave-uniform
      int sy = g >> 1, sx = g & 1;
      float a9[9];
      #pragma unroll
      for (int i = 0; i < 9; ++i) a9[i] = 0.f;
      const float* wbase = ws + OFF_D2R + co;
      for (int ci = h*32; ci < h*32+32; ++ci) {
        float w[9];
        #pragma unroll
        for (int k = 0; k < 9; ++k) w[k] = wbase[(ci*9+k)*32];
        const float* base = &R1[ci*38];
        #pragma unroll
        for (int wy = 0; wy < 5; ++wy) {
          int ry = sy*3 - 1 + wy;
          if (ry < 0 || ry > 5) continue;              // wave-uniform
          const float* row = base + ry*6 + sx*3;
          float r[5];
          if (sx == 0) {                                // wave-uniform
            r[0] = 0.f; r[1] = row[0]; r[2] = row[1]; r[3] = row[2]; r[4] = row[3];
          } else {
            r[0] = row[-1]; r[1] = row[0]; r[2] = row[1]; r[3] = row[2]; r[4] = 0.f;
          }
          #pragma unroll
          for (int y = 0; y < 3; ++y) {
            int d = wy - 1 - y + 1;                     // = ry - (sy*3+y) + 1
            if (d >= 0 && d < 3) {
              #pragma unroll
              for (int xx = 0; xx < 3; ++xx)
                #pragma unroll
                for (int dx = 0; dx < 3; ++dx) a9[y*3+xx] += r[xx+dx] * w[d*3+dx];
            }
          }
        }
      }
      __syncthreads();                 // R1 reads done
      if (h) {
        #pragma unroll
        for (int i = 0; i < 9; ++i) PS[(g*32 + co)*9 + i] = a9[i];
      }
      __syncthreads();
      if (!h) {
        float bias = d2b[co];
        #pragma unroll
        for (int i = 0; i < 9; ++i) a9[i] += PS[(g*32 + co)*9 + i];
        #pragma unroll
        for (int yy = 0; yy < 3; ++yy)
          #pragma unroll
          for (int xx = 0; xx < 3; ++xx) {
            float v = a9[yy*3+xx] + bias; v = v > 0.f ? v : 0.f;
            int rr = sy*3 + yy, cc_ = sx*3 + xx;
            int base = co*146 + (2*rr)*12 + 2*cc_;
            R0[base] = v; R0[base+1] = v; R0[base+12] = v; R0[base+13] = v;
          }
      }
    }
    __syncthreads();

    // ---- D3 (32->1, 12x12) + relu + upsample -> out ----
    if (t < 144) {
      int yy = t / 12, xx = t - yy*12;
      const float* w3 = ws + OFF_D3R;
      float acc = d3b[0];
      for (int ci = 0; ci < 32; ++ci) {
        const float* base = &R0[ci*146];
        #pragma unroll
        for (int dy = 0; dy < 3; ++dy) {
          int ry = yy - 1 + dy;
          int ryc = ry < 0 ? 0 : (ry > 11 ? 11 : ry);
          bool rok = (ry >= 0 && ry < 12);
          #pragma unroll
          for (int dx = 0; dx < 3; ++dx) {
            int rx = xx - 1 + dx;
            int rxc = rx < 0 ? 0 : (rx > 11 ? 11 : rx);
            float v = base[ryc*12 + rxc];
            v = (rok && rx >= 0 && rx < 12) ? v : 0.f;
            acc += v * w3[ci*9 + dy*3 + dx];
          }
        }
      }
      float v = acc > 0.f ? acc : 0.f;
      float* ob = out + (size_t)(s0 + s) * 576;
      int o0 = (2*yy)*24 + 2*xx;
      ob[o0] = v; ob[o0+1] = v; ob[o0+24] = v; ob[o0+25] = v;
    }
  }
}

extern "C" void kernel_launch(void* const* d_in, const int* in_sizes, int n_in,
                              void* d_out, int out_size, void* d_ws, size_t ws_size,
                              hipStream_t stream) {
  const float* x   = (const float*)d_in[0];
  const float* c1w = (const float*)d_in[1];
  const float* c1b = (const float*)d_in[2];
  const float* c2w = (const float*)d_in[3];
  const float* c2b = (const float*)d_in[4];
  const float* c3w = (const float*)d_in[5];
  const float* c3b = (const float*)d_in[6];
  const float* efw = (const float*)d_in[7];
  const float* efb = (const float*)d_in[8];
  const float* cb  = (const float*)d_in[9];
  const float* dfw = (const float*)d_in[10];
  const float* dfb = (const float*)d_in[11];
  const float* dw1 = (const float*)d_in[12];
  const float* db1 = (const float*)d_in[13];
  const float* dw2 = (const float*)d_in[14];
  const float* db2 = (const float*)d_in[15];
  const float* dw3 = (const float*)d_in[16];
  const float* db3 = (const float*)d_in[17];
  float* ws = (float*)d_ws;
  float* z   = ws + OFF_Z;
  int*   ids = (int*)(ws + OFF_IDS);
  float* outp = (float*)d_out;
  int B = in_sizes[0] / 576;

  vq_prep<<<(WS_WEIGHTS + 255) / 256, 256, 0, stream>>>(c1w, c2w, c3w, efw, cb, dfw, dw1, dw2, dw3, ws);
  vq_enc<<<B/2, 256, 0, stream>>>(x, c1b, c2b, c3b, efb, ws, z);
  vq_argmin<<<B/16, 256, 0, stream>>>(z, ws, ids);
  vq_dec<<<B/2, 256, 0, stream>>>(cb, dfb, db1, db2, db3, ws, ids, outp);
}

// Round 3
// 1152.992 us; speedup vs baseline: 1.7881x; 1.6139x over previous
//
#include <hip/hip_runtime.h>

typedef __attribute__((ext_vector_type(8))) short short8;
typedef __attribute__((ext_vector_type(4))) float f32x4;
typedef unsigned short ushort_t;
typedef unsigned int uint_t;

// ---------------- workspace layout (float offsets) ----------------
#define OFF_W1R   0
#define OFF_W2R   288
#define OFF_W3R   (288+18432)            // 18720
#define OFF_EWT   (18720+73728)          // 92448   ewt[k][128j] (legacy, unused)
#define OFF_CT    (92448+147456)         // 239904  ct[k][1024cw] (legacy, unused)
#define OFF_CC    (239904+131072)        // 370976  cc[1024]
#define OFF_DWT   (370976+1024)          // 372000  dwt[k][1152j]
#define OFF_D1R   (372000+147456)        // 519456
#define OFF_D2R   (519456+73728)         // 593184
#define OFF_D3R   (593184+18432)         // 611616
#define WS_WEIGHTS (611616+288)          // 611904
// new regions:
#define OFF_W2BF  WS_WEIGHTS             // 36864 ushort (hi|lo planes of conv2 w) = 18432 fl
#define OFF_W3BF  (OFF_W2BF+18432)       // 147456 ushort = 73728 fl
#define OFF_H     (OFF_W3BF+73728)       // h [8192][1152] fp32
#define OFF_IDSN  (OFF_H+8192*1152)      // ids [8192] int

__device__ __forceinline__ ushort_t f2bf(float v) {
  uint_t u = __float_as_uint(v);
  return (ushort_t)((u + 0x7FFFu + ((u >> 16) & 1u)) >> 16);
}
__device__ __forceinline__ float bf2f(ushort_t b) {
  return __uint_as_float(((uint_t)b) << 16);
}

__global__ void vq_prep(const float* __restrict__ conv1_w, const float* __restrict__ conv2_w,
                        const float* __restrict__ conv3_w, const float* __restrict__ enc_fc_w,
                        const float* __restrict__ codebook, const float* __restrict__ dec_fc_w,
                        const float* __restrict__ dct1_w, const float* __restrict__ dct2_w,
                        const float* __restrict__ dct3_w, float* __restrict__ ws) {
  int i = blockIdx.x * blockDim.x + threadIdx.x;
  if (i >= WS_WEIGHTS) return;
  if (i < OFF_W2R) {
    int tap = i >> 5, co = i & 31;
    ws[i] = conv1_w[co*9 + tap];
  } else if (i < OFF_W3R) {
    int l = i - OFF_W2R;
    int co = l & 63, r = l >> 6, tap = r % 9, ci = r / 9;
    ws[i] = conv2_w[(co*32 + ci)*9 + tap];
  } else if (i < OFF_EWT) {
    int l = i - OFF_W3R;
    int co = l & 127, r = l >> 7, tap = r % 9, ci = r / 9;
    ws[i] = conv3_w[(co*64 + ci)*9 + tap];
  } else if (i < OFF_CT) {
    int l = i - OFF_EWT;
    int j = l & 127, k = l >> 7;
    ws[i] = enc_fc_w[j*1152 + k];
  } else if (i < OFF_CC) {
    int l = i - OFF_CT;
    int k = l & 1023, j = l >> 10;
    ws[i] = codebook[k*128 + j];
  } else if (i < OFF_DWT) {
    int k = i - OFF_CC;
    float s = 0.f;
    for (int j = 0; j < 128; ++j) { float v = codebook[k*128+j]; s += v*v; }
    ws[i] = s;
  } else if (i < OFF_D1R) {
    int l = i - OFF_DWT;
    int j = l % 1152, k = l / 1152;
    ws[i] = dec_fc_w[j*128 + k];
  } else if (i < OFF_D2R) {
    int l = i - OFF_D1R;
    int co = l & 63, r = l >> 6, tap = r % 9, ci = r / 9;
    ws[i] = dct1_w[(ci*64 + co)*9 + (8 - tap)];
  } else if (i < OFF_D3R) {
    int l = i - OFF_D2R;
    int co = l & 31, r = l >> 5, tap = r % 9, ci = r / 9;
    ws[i] = dct2_w[(ci*32 + co)*9 + (8 - tap)];
  } else {
    int l = i - OFF_D3R;
    int tap = l % 9, ci = l / 9;
    ws[i] = dct3_w[ci*9 + (8 - tap)];
  }
}

// bf16 hi/lo weight planes for MFMA convs: w2bf[plane][tap][co64][ch32], w3bf[plane][tap][co128][ch64]
__global__ void vq_prep2(const float* __restrict__ conv2_w, const float* __restrict__ conv3_w,
                         float* __restrict__ ws) {
  int i = blockIdx.x * blockDim.x + threadIdx.x;
  ushort_t* W2 = (ushort_t*)(ws + OFF_W2BF);
  ushort_t* W3 = (ushort_t*)(ws + OFF_W3BF);
  if (i < 18432) {
    int tap = i >> 11, r = i & 2047, co = r >> 5, ch = r & 31;
    float v = conv2_w[(co*32 + ch)*9 + tap];
    ushort_t hb = f2bf(v);
    W2[i] = hb; W2[18432 + i] = f2bf(v - bf2f(hb));
  } else if (i < 92160) {
    int j = i - 18432;
    int tap = j >> 13, r = j & 8191, co = r >> 6, ch = r & 63;
    float v = conv3_w[(co*64 + ch)*9 + tap];
    ushort_t hb = f2bf(v);
    W3[j] = hb; W3[73728 + j] = f2bf(v - bf2f(hb));
  }
}

// ---------------- encoder: 1 sample/block, conv2/conv3 via MFMA bf16x3 ----------------
__global__ __launch_bounds__(256, 3) void vq_enc(
    const float* __restrict__ x,
    const float* __restrict__ b1, const float* __restrict__ b2, const float* __restrict__ b3,
    const float* __restrict__ ws, float* __restrict__ hout)
{
  __shared__ ushort_t R0h[7840], R0l[7840];   // conv1-out [14][14][40] (ring-padded, ch-pad)
  __shared__ ushort_t C3h[4608], C3l[4608];   // conv2-out [8][8][72]
  __shared__ float XT[624];                    // x [24][26] col-padded
  const int t = threadIdx.x;
  const int b = blockIdx.x;

  for (int i = t; i < 3920; i += 256) { ((uint_t*)R0h)[i] = 0u; ((uint_t*)R0l)[i] = 0u; }
  for (int i = t; i < 2304; i += 256) { ((uint_t*)C3h)[i] = 0u; ((uint_t*)C3l)[i] = 0u; }
  const float* xb = x + (size_t)b * 576;
  for (int i = t; i < 624; i += 256) {
    int row = i / 26, col = i - row * 26;
    XT[i] = (col >= 1 && col <= 24) ? xb[row*24 + col - 1] : 0.f;
  }
  __syncthreads();

  // ---- conv1 (1->32) + relu + pool (vector fp32) -> R0 hi/lo planes ----
  {
    int co = t & 31, g = t >> 5, gy = g >> 1, gx = g & 1;
    float w[9];
    #pragma unroll
    for (int k = 0; k < 9; ++k) w[k] = ws[OFF_W1R + k*32 + co];
    float bias = b1[co];
    #pragma unroll
    for (int pr = 0; pr < 3; ++pr) {
      int Y = gy*6 + pr*2;
      float a0[12], a1[12];
      #pragma unroll
      for (int i = 0; i < 12; ++i) { a0[i] = 0.f; a1[i] = 0.f; }
      #pragma unroll
      for (int wy = 0; wy < 4; ++wy) {
        int ry = Y - 1 + wy;
        if (ry < 0 || ry > 23) continue;     // wave-uniform (gy uniform in-wave)
        const float2* rp = (const float2*)&XT[ry*26 + gx*12];
        float r[14];
        #pragma unroll
        for (int k = 0; k < 7; ++k) { float2 p = rp[k]; r[2*k] = p.x; r[2*k+1] = p.y; }
        if (wy < 3) {
          #pragma unroll
          for (int xx = 0; xx < 12; ++xx)
            #pragma unroll
            for (int dx = 0; dx < 3; ++dx) a0[xx] += r[xx+dx] * w[wy*3+dx];
        }
        if (wy >= 1) {
          #pragma unroll
          for (int xx = 0; xx < 12; ++xx)
            #pragma unroll
            for (int dx = 0; dx < 3; ++dx) a1[xx] += r[xx+dx] * w[(wy-1)*3+dx];
        }
      }
      #pragma unroll
      for (int pc = 0; pc < 6; ++pc) {
        float m = fmaxf(fmaxf(a0[2*pc], a0[2*pc+1]), fmaxf(a1[2*pc], a1[2*pc+1]));
        float v = m + bias; v = v > 0.f ? v : 0.f;
        int row = gy*3 + pr, colp = gx*6 + pc;
        int addr = ((row+1)*14 + (colp+1))*40 + co;
        ushort_t hb = f2bf(v);
        R0h[addr] = hb;
        R0l[addr] = f2bf(v - bf2f(hb));
      }
    }
  }
  __syncthreads();

  const int lane = t & 63, quad = lane >> 4, col = lane & 15;
  const int wv = t >> 6;

  // ---- conv2 (32->64, K=288) MFMA, M=144 pool-grouped (+pad to 160) ----
  {
    const int h = wv & 1, p = wv >> 1;          // m-half, n-pair
    const ushort_t* W2 = (const ushort_t*)(ws + OFF_W2BF);
    int baseA[5];
    #pragma unroll
    for (int mi = 0; mi < 5; ++mi) {
      int m = (h*5 + mi)*16 + col; if (m > 143) m = 143;
      int cell = m >> 2, sub = m & 3;
      int opy = cell / 6, opx = cell - opy*6;
      int y = 2*opy + (sub >> 1), xx = 2*opx + (sub & 1);
      baseA[mi] = (y*14 + xx)*40 + quad*8;
    }
    f32x4 acc[5][2];
    #pragma unroll
    for (int mi = 0; mi < 5; ++mi) { acc[mi][0] = (f32x4)0.f; acc[mi][1] = (f32x4)0.f; }
    const int co0 = p*32 + col, co1 = co0 + 16;
    #pragma unroll
    for (int t9 = 0; t9 < 9; ++t9) {
      const int TAPOFF = ((t9/3)*14 + (t9%3))*40;
      int bidx = t9*2048 + quad*8;
      short8 Bh0 = *(const short8*)(W2 + bidx + co0*32);
      short8 Bh1 = *(const short8*)(W2 + bidx + co1*32);
      short8 Bl0 = *(const short8*)(W2 + 18432 + bidx + co0*32);
      short8 Bl1 = *(const short8*)(W2 + 18432 + bidx + co1*32);
      #pragma unroll
      for (int mi = 0; mi < 5; ++mi) {
        int a = baseA[mi] + TAPOFF;
        short8 Ah = *(const short8*)(R0h + a);
        short8 Al = *(const short8*)(R0l + a);
        acc[mi][0] = __builtin_amdgcn_mfma_f32_16x16x32_bf16(Al, Bh0, acc[mi][0], 0, 0, 0);
        acc[mi][0] = __builtin_amdgcn_mfma_f32_16x16x32_bf16(Ah, Bl0, acc[mi][0], 0, 0, 0);
        acc[mi][0] = __builtin_amdgcn_mfma_f32_16x16x32_bf16(Ah, Bh0, acc[mi][0], 0, 0, 0);
        acc[mi][1] = __builtin_amdgcn_mfma_f32_16x16x32_bf16(Al, Bh1, acc[mi][1], 0, 0, 0);
        acc[mi][1] = __builtin_amdgcn_mfma_f32_16x16x32_bf16(Ah, Bl1, acc[mi][1], 0, 0, 0);
        acc[mi][1] = __builtin_amdgcn_mfma_f32_16x16x32_bf16(Ah, Bh1, acc[mi][1], 0, 0, 0);
      }
    }
    // epilogue: in-register 2x2 pool + bias + relu -> C3 planes (bf16 hi/lo)
    #pragma unroll
    for (int mi = 0; mi < 5; ++mi) {
      int cell = (h*5 + mi)*4 + quad;           // pooled 6x6 cell
      if (cell < 36) {
        int opy = cell / 6, opx = cell - opy*6;
        int wa = ((opy+1)*8 + (opx+1))*72;
        #pragma unroll
        for (int j = 0; j < 2; ++j) {
          int ch = j ? co1 : co0;
          f32x4 a = acc[mi][j];
          float v = fmaxf(fmaxf(a.x, a.y), fmaxf(a.z, a.w)) + b2[ch];
          v = v > 0.f ? v : 0.f;
          ushort_t hb = f2bf(v);
          C3h[wa + ch] = hb;
          C3l[wa + ch] = f2bf(v - bf2f(hb));
        }
      }
    }
  }
  __syncthreads();

  // ---- conv3 (64->128, K=576) MFMA, M=36 pool-grouped (+pad to 48) ----
  {
    const ushort_t* W3 = (const ushort_t*)(ws + OFF_W3BF);
    int baseA[3];
    #pragma unroll
    for (int mt = 0; mt < 3; ++mt) {
      int m = mt*16 + col; if (m > 35) m = 35;
      int cell = m >> 2, sub = m & 3;
      int opy = cell / 3, opx = cell - opy*3;
      int y = 2*opy + (sub >> 1), xx = 2*opx + (sub & 1);
      baseA[mt] = (y*8 + xx)*72 + quad*8;
    }
    f32x4 acc[3][2];
    #pragma unroll
    for (int mt = 0; mt < 3; ++mt) { acc[mt][0] = (f32x4)0.f; acc[mt][1] = (f32x4)0.f; }
    const int co0 = wv*16 + col, co1 = co0 + 64;
    #pragma unroll
    for (int ks = 0; ks < 18; ++ks) {
      const int t9 = ks >> 1, ch0 = (ks & 1)*32;
      const int TAPOFF = ((t9/3)*8 + (t9%3))*72;
      int bidx = t9*8192 + ch0 + quad*8;
      short8 Bh0 = *(const short8*)(W3 + bidx + co0*64);
      short8 Bh1 = *(const short8*)(W3 + bidx + co1*64);
      short8 Bl0 = *(const short8*)(W3 + 73728 + bidx + co0*64);
      short8 Bl1 = *(const short8*)(W3 + 73728 + bidx + co1*64);
      #pragma unroll
      for (int mt = 0; mt < 3; ++mt) {
        int a = baseA[mt] + TAPOFF + ch0;
        short8 Ah = *(const short8*)(C3h + a);
        short8 Al = *(const short8*)(C3l + a);
        acc[mt][0] = __builtin_amdgcn_mfma_f32_16x16x32_bf16(Al, Bh0, acc[mt][0], 0, 0, 0);
        acc[mt][0] = __builtin_amdgcn_mfma_f32_16x16x32_bf16(Ah, Bl0, acc[mt][0], 0, 0, 0);
        acc[mt][0] = __builtin_amdgcn_mfma_f32_16x16x32_bf16(Ah, Bh0, acc[mt][0], 0, 0, 0);
        acc[mt][1] = __builtin_amdgcn_mfma_f32_16x16x32_bf16(Al, Bh1, acc[mt][1], 0, 0, 0);
        acc[mt][1] = __builtin_amdgcn_mfma_f32_16x16x32_bf16(Ah, Bl1, acc[mt][1], 0, 0, 0);
        acc[mt][1] = __builtin_amdgcn_mfma_f32_16x16x32_bf16(Ah, Bh1, acc[mt][1], 0, 0, 0);
      }
    }
    // epilogue: pool + bias + relu -> h[b][ch*9 + cell] (fp32 global)
    float* hb_ = hout + (size_t)b * 1152;
    #pragma unroll
    for (int mt = 0; mt < 3; ++mt) {
      int cell = mt*4 + quad;                   // pooled 3x3 cell
      if (cell < 9) {
        #pragma unroll
        for (int j = 0; j < 2; ++j) {
          int ch = j ? co1 : co0;
          f32x4 a = acc[mt][j];
          float v = fmaxf(fmaxf(a.x, a.y), fmaxf(a.z, a.w)) + b3[ch];
          v = v > 0.f ? v : 0.f;
          hb_[ch*9 + cell] = v;
        }
      }
    }
  }
}

// ---------------- fused enc_fc + argmin: 16 samples/block (fp32 vector) ----------------
__global__ __launch_bounds__(256, 2) void vq_fc_argmin(
    const float* __restrict__ efw, const float* __restrict__ efb,
    const float* __restrict__ cb, const float* __restrict__ ws,
    const float* __restrict__ h, int* __restrict__ ids)
{
  __shared__ float HT[18432];    // h [16][1152], later z [16][128] overlay
  __shared__ float WVs[64];
  __shared__ int   WIs[64];
  const int t = threadIdx.x;
  const int sb = blockIdx.x * 16;

  const float4* src = (const float4*)(h + (size_t)sb * 1152);
  for (int i = t; i < 4608; i += 256) ((float4*)HT)[i] = src[i];
  __syncthreads();

  // z = h @ efw^T + b : thread (j = t&127, g = t>>7) handles 8 samples
  const int j = t & 127, g = t >> 7;
  float acc[8];
  #pragma unroll
  for (int u = 0; u < 8; ++u) acc[u] = 0.f;
  const float* wj = efw + (size_t)j * 1152;
  for (int k4 = 0; k4 < 1152; k4 += 4) {
    float4 wvv = *(const float4*)(wj + k4);
    const float* hp = &HT[g*9216 + k4];
    #pragma unroll
    for (int u = 0; u < 8; ++u) {
      float4 hv = *(const float4*)(hp + u*1152);
      acc[u] += wvv.x*hv.x + wvv.y*hv.y + wvv.z*hv.z + wvv.w*hv.w;
    }
  }
  float bias = efb[j];
  __syncthreads();
  #pragma unroll
  for (int u = 0; u < 8; ++u) HT[(g*8 + u)*128 + j] = acc[u] + bias;
  __syncthreads();

  // argmin over 1024 codewords: thread handles cw = c*256 + t
  float bestv[16]; int besti[16];
  #pragma unroll
  for (int s = 0; s < 16; ++s) { bestv[s] = 3.4e38f; besti[s] = 0; }
  for (int c = 0; c < 4; ++c) {
    int cw = c*256 + t;
    float d[16];
    #pragma unroll
    for (int s = 0; s < 16; ++s) d[s] = 0.f;
    const float* cp = cb + (size_t)cw * 128;
    for (int k4 = 0; k4 < 128; k4 += 4) {
      float4 cv = *(const float4*)(cp + k4);
      #pragma unroll
      for (int s = 0; s < 16; ++s) {
        float4 zv = *(const float4*)(&HT[s*128 + k4]);
        d[s] += cv.x*zv.x + cv.y*zv.y + cv.z*zv.z + cv.w*zv.w;
      }
    }
    float ccv = ws[OFF_CC + cw];
    #pragma unroll
    for (int s = 0; s < 16; ++s) {
      float dist = ccv - 2.f*d[s];
      if (dist < bestv[s]) { bestv[s] = dist; besti[s] = cw; }
    }
  }
  const int lane = t & 63, wid = t >> 6;
  #pragma unroll
  for (int s = 0; s < 16; ++s) {
    float v = bestv[s]; int ii = besti[s];
    #pragma unroll
    for (int off = 32; off >= 1; off >>= 1) {
      float v2 = __shfl_xor(v, off); int i2 = __shfl_xor(ii, off);
      if (v2 < v || (v2 == v && i2 < ii)) { v = v2; ii = i2; }
    }
    if (lane == 0) { WVs[wid*16 + s] = v; WIs[wid*16 + s] = ii; }
  }
  __syncthreads();
  if (t < 16) {
    float v = WVs[t]; int ii = WIs[t];
    #pragma unroll
    for (int w2 = 1; w2 < 4; ++w2) {
      float v2 = WVs[w2*16 + t]; int i2 = WIs[w2*16 + t];
      if (v2 < v || (v2 == v && i2 < ii)) { v = v2; ii = i2; }
    }
    ids[sb + t] = ii;
  }
}

// ---------------- decoder: 2 samples per block (unchanged from round 2) ----------------
__global__ __launch_bounds__(256, 4) void vq_dec(
    const float* __restrict__ codebook, const float* __restrict__ decb,
    const float* __restrict__ d1b, const float* __restrict__ d2b, const float* __restrict__ d3b,
    const float* __restrict__ ws, const int* __restrict__ ids, float* __restrict__ out)
{
  __shared__ float DB[2304];
  __shared__ float R1[2432];
  __shared__ float R0[4736];
  __shared__ float ZQ[256];
  __shared__ int IDX[2];
  const int t = threadIdx.x;
  const int s0 = blockIdx.x * 2;

  if (t < 2) IDX[t] = ids[s0 + t];
  __syncthreads();
  { int s = t >> 7, j = t & 127; ZQ[s*128 + j] = codebook[(size_t)IDX[s]*128 + j]; }
  __syncthreads();

  #pragma unroll
  for (int p = 0; p < 5; ++p) {
    int j = t + p*256;
    if (j < 1152) {
      float a0 = decb[j], a1 = a0;
      const float* wb = ws + OFF_DWT + j;
      #pragma unroll 4
      for (int k = 0; k < 128; ++k) {
        float wv = wb[k*1152];
        a0 += wv * ZQ[k];
        a1 += wv * ZQ[128 + k];
      }
      DB[j] = a0; DB[1152 + j] = a1;
    }
  }

  for (int s = 0; s < 2; ++s) {
    __syncthreads();
    const float* F = &DB[s*1152];
    float* PS = &DB[s*1152];

    {
      int co = t & 63, g = t >> 6;
      float a9[9];
      #pragma unroll
      for (int i = 0; i < 9; ++i) a9[i] = 0.f;
      const float* wbase = ws + OFF_D1R + co;
      for (int ci = g*32; ci < g*32+32; ++ci) {
        float w[9];
        #pragma unroll
        for (int k = 0; k < 9; ++k) w[k] = wbase[(ci*9+k)*64];
        const float* fin = F + ci*9;
        #pragma unroll
        for (int ry = 0; ry < 3; ++ry) {
          float r[5];
          r[0] = 0.f; r[4] = 0.f;
          r[1] = fin[ry*3]; r[2] = fin[ry*3+1]; r[3] = fin[ry*3+2];
          #pragma unroll
          for (int y = 0; y < 3; ++y) {
            int d = ry - y + 1;
            if (d >= 0 && d < 3) {
              #pragma unroll
              for (int xx = 0; xx < 3; ++xx)
                #pragma unroll
                for (int dx = 0; dx < 3; ++dx) a9[y*3+xx] += r[xx+dx] * w[d*3+dx];
            }
          }
        }
      }
      __syncthreads();
      if (g) {
        #pragma unroll
        for (int i = 0; i < 9; ++i) R0[((g-1)*64 + co)*9 + i] = a9[i];
      }
      __syncthreads();
      if (!g) {
        float bias = d1b[co];
        #pragma unroll
        for (int i = 0; i < 9; ++i)
          a9[i] += R0[co*9 + i] + R0[(64+co)*9 + i] + R0[(128+co)*9 + i];
        #pragma unroll
        for (int yy = 0; yy < 3; ++yy)
          #pragma unroll
          for (int xx = 0; xx < 3; ++xx) {
            float v = a9[yy*3+xx] + bias; v = v > 0.f ? v : 0.f;
            int base = co*38 + (2*yy)*6 + 2*xx;
            R1[base] = v; R1[base+1] = v; R1[base+6] = v; R1[base+7] = v;
          }
      }
    }
    __syncthreads();

    {
      int co = t & 31, hh = (t >> 5) & 1, g = t >> 6;
      int sy = g >> 1, sx = g & 1;
      float a9[9];
      #pragma unroll
      for (int i = 0; i < 9; ++i) a9[i] = 0.f;
      const float* wbase = ws + OFF_D2R + co;
      for (int ci = hh*32; ci < hh*32+32; ++ci) {
        float w[9];
        #pragma unroll
        for (int k = 0; k < 9; ++k) w[k] = wbase[(ci*9+k)*32];
        const float* base = &R1[ci*38];
        #pragma unroll
        for (int wy = 0; wy < 5; ++wy) {
          int ry = sy*3 - 1 + wy;
          if (ry < 0 || ry > 5) continue;
          const float* row = base + ry*6 + sx*3;
          float r[5];
          if (sx == 0) {
            r[0] = 0.f; r[1] = row[0]; r[2] = row[1]; r[3] = row[2]; r[4] = row[3];
          } else {
            r[0] = row[-1]; r[1] = row[0]; r[2] = row[1]; r[3] = row[2]; r[4] = 0.f;
          }
          #pragma unroll
          for (int y = 0; y < 3; ++y) {
            int d = wy - 1 - y + 1;
            if (d >= 0 && d < 3) {
              #pragma unroll
              for (int xx = 0; xx < 3; ++xx)
                #pragma unroll
                for (int dx = 0; dx < 3; ++dx) a9[y*3+xx] += r[xx+dx] * w[d*3+dx];
            }
          }
        }
      }
      __syncthreads();
      if (hh) {
        #pragma unroll
        for (int i = 0; i < 9; ++i) PS[(g*32 + co)*9 + i] = a9[i];
      }
      __syncthreads();
      if (!hh) {
        float bias = d2b[co];
        #pragma unroll
        for (int i = 0; i < 9; ++i) a9[i] += PS[(g*32 + co)*9 + i];
        #pragma unroll
        for (int yy = 0; yy < 3; ++yy)
          #pragma unroll
          for (int xx = 0; xx < 3; ++xx) {
            float v = a9[yy*3+xx] + bias; v = v > 0.f ? v : 0.f;
            int rr = sy*3 + yy, cc_ = sx*3 + xx;
            int base = co*146 + (2*rr)*12 + 2*cc_;
            R0[base] = v; R0[base+1] = v; R0[base+12] = v; R0[base+13] = v;
          }
      }
    }
    __syncthreads();

    if (t < 144) {
      int yy = t / 12, xx = t - yy*12;
      const float* w3 = ws + OFF_D3R;
      float acc = d3b[0];
      for (int ci = 0; ci < 32; ++ci) {
        const float* base = &R0[ci*146];
        #pragma unroll
        for (int dy = 0; dy < 3; ++dy) {
          int ry = yy - 1 + dy;
          int ryc = ry < 0 ? 0 : (ry > 11 ? 11 : ry);
          bool rok = (ry >= 0 && ry < 12);
          #pragma unroll
          for (int dx = 0; dx < 3; ++dx) {
            int rx = xx - 1 + dx;
            int rxc = rx < 0 ? 0 : (rx > 11 ? 11 : rx);
            float v = base[ryc*12 + rxc];
            v = (rok && rx >= 0 && rx < 12) ? v : 0.f;
            acc += v * w3[ci*9 + dy*3 + dx];
          }
        }
      }
      float v = acc > 0.f ? acc : 0.f;
      float* ob = out + (size_t)(s0 + s) * 576;
      int o0 = (2*yy)*24 + 2*xx;
      ob[o0] = v; ob[o0+1] = v; ob[o0+24] = v; ob[o0+25] = v;
    }
  }
}

extern "C" void kernel_launch(void* const* d_in, const int* in_sizes, int n_in,
                              void* d_out, int out_size, void* d_ws, size_t ws_size,
                              hipStream_t stream) {
  const float* x   = (const float*)d_in[0];
  const float* c1w = (const float*)d_in[1];
  const float* c1b = (const float*)d_in[2];
  const float* c2w = (const float*)d_in[3];
  const float* c2b = (const float*)d_in[4];
  const float* c3w = (const float*)d_in[5];
  const float* c3b = (const float*)d_in[6];
  const float* efw = (const float*)d_in[7];
  const float* efb = (const float*)d_in[8];
  const float* cb  = (const float*)d_in[9];
  const float* dfw = (const float*)d_in[10];
  const float* dfb = (const float*)d_in[11];
  const float* dw1 = (const float*)d_in[12];
  const float* db1 = (const float*)d_in[13];
  const float* dw2 = (const float*)d_in[14];
  const float* db2 = (const float*)d_in[15];
  const float* dw3 = (const float*)d_in[16];
  const float* db3 = (const float*)d_in[17];
  float* ws = (float*)d_ws;
  float* h   = ws + OFF_H;
  int*   ids = (int*)(ws + OFF_IDSN);
  float* outp = (float*)d_out;
  int B = in_sizes[0] / 576;

  vq_prep<<<(WS_WEIGHTS + 255) / 256, 256, 0, stream>>>(c1w, c2w, c3w, efw, cb, dfw, dw1, dw2, dw3, ws);
  vq_prep2<<<(92160 + 255) / 256, 256, 0, stream>>>(c2w, c3w, ws);
  vq_enc<<<B, 256, 0, stream>>>(x, c1b, c2b, c3b, ws, h);
  vq_fc_argmin<<<B/16, 256, 0, stream>>>(efw, efb, cb, ws, h, ids);
  vq_dec<<<B/2, 256, 0, stream>>>(cb, dfb, db1, db2, db3, ws, ids, outp);
}

// Round 4
// 728.325 us; speedup vs baseline: 2.8306x; 1.5831x over previous
//
#include <hip/hip_runtime.h>

typedef __attribute__((ext_vector_type(8))) short short8;
typedef __attribute__((ext_vector_type(4))) float f32x4;
typedef unsigned short ushort_t;
typedef unsigned int uint_t;

// ---------------- workspace layout (float offsets) ----------------
#define OFF_W1R   0
#define OFF_W2R   288
#define OFF_W3R   (288+18432)            // 18720
#define OFF_EWT   (18720+73728)          // 92448   (legacy, unused)
#define OFF_CT    (92448+147456)         // 239904  (legacy, unused)
#define OFF_CC    (239904+131072)        // 370976  cc[1024]
#define OFF_DWT   (370976+1024)          // 372000  dwt[k][1152j]
#define OFF_D1R   (372000+147456)        // 519456
#define OFF_D2R   (519456+73728)         // 593184
#define OFF_D3R   (593184+18432)         // 611616
#define WS_WEIGHTS (611616+288)          // 611904
#define OFF_W2BF  WS_WEIGHTS             // bf16 hi/lo conv2 w: 36864 ushort = 18432 fl
#define OFF_W3BF  (OFF_W2BF+18432)       // bf16 hi/lo conv3 w: 147456 ushort = 73728 fl
#define OFF_H     (OFF_W3BF+73728)       // h [8192][1152] fp32 (dead after fc_argmin)
#define OFF_TABLE OFF_H                  // decoded table [1024][576] overlays dead h
#define OFF_IDSN  (OFF_H+8192*1152)      // ids [8192] int

__device__ __forceinline__ ushort_t f2bf(float v) {
  uint_t u = __float_as_uint(v);
  return (ushort_t)((u + 0x7FFFu + ((u >> 16) & 1u)) >> 16);
}
__device__ __forceinline__ float bf2f(ushort_t b) {
  return __uint_as_float(((uint_t)b) << 16);
}

__global__ void vq_prep(const float* __restrict__ conv1_w, const float* __restrict__ conv2_w,
                        const float* __restrict__ conv3_w, const float* __restrict__ enc_fc_w,
                        const float* __restrict__ codebook, const float* __restrict__ dec_fc_w,
                        const float* __restrict__ dct1_w, const float* __restrict__ dct2_w,
                        const float* __restrict__ dct3_w, float* __restrict__ ws) {
  int i = blockIdx.x * blockDim.x + threadIdx.x;
  if (i >= WS_WEIGHTS) return;
  if (i < OFF_W2R) {
    int tap = i >> 5, co = i & 31;
    ws[i] = conv1_w[co*9 + tap];
  } else if (i < OFF_W3R) {
    int l = i - OFF_W2R;
    int co = l & 63, r = l >> 6, tap = r % 9, ci = r / 9;
    ws[i] = conv2_w[(co*32 + ci)*9 + tap];
  } else if (i < OFF_EWT) {
    int l = i - OFF_W3R;
    int co = l & 127, r = l >> 7, tap = r % 9, ci = r / 9;
    ws[i] = conv3_w[(co*64 + ci)*9 + tap];
  } else if (i < OFF_CC) {
    return;  // legacy regions unused
  } else if (i < OFF_DWT) {
    int k = i - OFF_CC;
    float s = 0.f;
    for (int j = 0; j < 128; ++j) { float v = codebook[k*128+j]; s += v*v; }
    ws[i] = s;
  } else if (i < OFF_D1R) {
    int l = i - OFF_DWT;
    int j = l % 1152, k = l / 1152;
    ws[i] = dec_fc_w[j*128 + k];
  } else if (i < OFF_D2R) {
    int l = i - OFF_D1R;
    int co = l & 63, r = l >> 6, tap = r % 9, ci = r / 9;
    ws[i] = dct1_w[(ci*64 + co)*9 + (8 - tap)];
  } else if (i < OFF_D3R) {
    int l = i - OFF_D2R;
    int co = l & 31, r = l >> 5, tap = r % 9, ci = r / 9;
    ws[i] = dct2_w[(ci*32 + co)*9 + (8 - tap)];
  } else {
    int l = i - OFF_D3R;
    int tap = l % 9, ci = l / 9;
    ws[i] = dct3_w[ci*9 + (8 - tap)];
  }
}

// bf16 hi/lo weight planes for MFMA convs
__global__ void vq_prep2(const float* __restrict__ conv2_w, const float* __restrict__ conv3_w,
                         float* __restrict__ ws) {
  int i = blockIdx.x * blockDim.x + threadIdx.x;
  ushort_t* W2 = (ushort_t*)(ws + OFF_W2BF);
  ushort_t* W3 = (ushort_t*)(ws + OFF_W3BF);
  if (i < 18432) {
    int tap = i >> 11, r = i & 2047, co = r >> 5, ch = r & 31;
    float v = conv2_w[(co*32 + ch)*9 + tap];
    ushort_t hb = f2bf(v);
    W2[i] = hb; W2[18432 + i] = f2bf(v - bf2f(hb));
  } else if (i < 92160) {
    int j = i - 18432;
    int tap = j >> 13, r = j & 8191, co = r >> 6, ch = r & 63;
    float v = conv3_w[(co*64 + ch)*9 + tap];
    ushort_t hb = f2bf(v);
    W3[j] = hb; W3[73728 + j] = f2bf(v - bf2f(hb));
  }
}

// ---------------- encoder: 1 sample/block, conv2/conv3 via MFMA bf16x3 ----------------
__global__ __launch_bounds__(256, 3) void vq_enc(
    const float* __restrict__ x,
    const float* __restrict__ b1, const float* __restrict__ b2, const float* __restrict__ b3,
    const float* __restrict__ ws, float* __restrict__ hout)
{
  __shared__ ushort_t R0h[7840], R0l[7840];   // conv1-out [14][14][40]
  __shared__ ushort_t C3h[4608], C3l[4608];   // conv2-out [8][8][72]
  __shared__ float XT[624];                    // x [24][26] col-padded
  const int t = threadIdx.x;
  const int b = blockIdx.x;

  for (int i = t; i < 3920; i += 256) { ((uint_t*)R0h)[i] = 0u; ((uint_t*)R0l)[i] = 0u; }
  for (int i = t; i < 2304; i += 256) { ((uint_t*)C3h)[i] = 0u; ((uint_t*)C3l)[i] = 0u; }
  const float* xb = x + (size_t)b * 576;
  for (int i = t; i < 624; i += 256) {
    int row = i / 26, col = i - row * 26;
    XT[i] = (col >= 1 && col <= 24) ? xb[row*24 + col - 1] : 0.f;
  }
  __syncthreads();

  // ---- conv1 (1->32) + relu + pool (vector fp32) ----
  {
    int co = t & 31, g = t >> 5, gy = g >> 1, gx = g & 1;
    float w[9];
    #pragma unroll
    for (int k = 0; k < 9; ++k) w[k] = ws[OFF_W1R + k*32 + co];
    float bias = b1[co];
    #pragma unroll
    for (int pr = 0; pr < 3; ++pr) {
      int Y = gy*6 + pr*2;
      float a0[12], a1[12];
      #pragma unroll
      for (int i = 0; i < 12; ++i) { a0[i] = 0.f; a1[i] = 0.f; }
      #pragma unroll
      for (int wy = 0; wy < 4; ++wy) {
        int ry = Y - 1 + wy;
        if (ry < 0 || ry > 23) continue;
        const float2* rp = (const float2*)&XT[ry*26 + gx*12];
        float r[14];
        #pragma unroll
        for (int k = 0; k < 7; ++k) { float2 p = rp[k]; r[2*k] = p.x; r[2*k+1] = p.y; }
        if (wy < 3) {
          #pragma unroll
          for (int xx = 0; xx < 12; ++xx)
            #pragma unroll
            for (int dx = 0; dx < 3; ++dx) a0[xx] += r[xx+dx] * w[wy*3+dx];
        }
        if (wy >= 1) {
          #pragma unroll
          for (int xx = 0; xx < 12; ++xx)
            #pragma unroll
            for (int dx = 0; dx < 3; ++dx) a1[xx] += r[xx+dx] * w[(wy-1)*3+dx];
        }
      }
      #pragma unroll
      for (int pc = 0; pc < 6; ++pc) {
        float m = fmaxf(fmaxf(a0[2*pc], a0[2*pc+1]), fmaxf(a1[2*pc], a1[2*pc+1]));
        float v = m + bias; v = v > 0.f ? v : 0.f;
        int row = gy*3 + pr, colp = gx*6 + pc;
        int addr = ((row+1)*14 + (colp+1))*40 + co;
        ushort_t hb = f2bf(v);
        R0h[addr] = hb;
        R0l[addr] = f2bf(v - bf2f(hb));
      }
    }
  }
  __syncthreads();

  const int lane = t & 63, quad = lane >> 4, col = lane & 15;
  const int wv = t >> 6;

  // ---- conv2 (32->64, K=288) MFMA ----
  {
    const int h = wv & 1, p = wv >> 1;
    const ushort_t* W2 = (const ushort_t*)(ws + OFF_W2BF);
    int baseA[5];
    #pragma unroll
    for (int mi = 0; mi < 5; ++mi) {
      int m = (h*5 + mi)*16 + col; if (m > 143) m = 143;
      int cell = m >> 2, sub = m & 3;
      int opy = cell / 6, opx = cell - opy*6;
      int y = 2*opy + (sub >> 1), xx = 2*opx + (sub & 1);
      baseA[mi] = (y*14 + xx)*40 + quad*8;
    }
    f32x4 acc[5][2];
    #pragma unroll
    for (int mi = 0; mi < 5; ++mi) { acc[mi][0] = (f32x4)0.f; acc[mi][1] = (f32x4)0.f; }
    const int co0 = p*32 + col, co1 = co0 + 16;
    #pragma unroll
    for (int t9 = 0; t9 < 9; ++t9) {
      const int TAPOFF = ((t9/3)*14 + (t9%3))*40;
      int bidx = t9*2048 + quad*8;
      short8 Bh0 = *(const short8*)(W2 + bidx + co0*32);
      short8 Bh1 = *(const short8*)(W2 + bidx + co1*32);
      short8 Bl0 = *(const short8*)(W2 + 18432 + bidx + co0*32);
      short8 Bl1 = *(const short8*)(W2 + 18432 + bidx + co1*32);
      #pragma unroll
      for (int mi = 0; mi < 5; ++mi) {
        int a = baseA[mi] + TAPOFF;
        short8 Ah = *(const short8*)(R0h + a);
        short8 Al = *(const short8*)(R0l + a);
        acc[mi][0] = __builtin_amdgcn_mfma_f32_16x16x32_bf16(Al, Bh0, acc[mi][0], 0, 0, 0);
        acc[mi][0] = __builtin_amdgcn_mfma_f32_16x16x32_bf16(Ah, Bl0, acc[mi][0], 0, 0, 0);
        acc[mi][0] = __builtin_amdgcn_mfma_f32_16x16x32_bf16(Ah, Bh0, acc[mi][0], 0, 0, 0);
        acc[mi][1] = __builtin_amdgcn_mfma_f32_16x16x32_bf16(Al, Bh1, acc[mi][1], 0, 0, 0);
        acc[mi][1] = __builtin_amdgcn_mfma_f32_16x16x32_bf16(Ah, Bl1, acc[mi][1], 0, 0, 0);
        acc[mi][1] = __builtin_amdgcn_mfma_f32_16x16x32_bf16(Ah, Bh1, acc[mi][1], 0, 0, 0);
      }
    }
    #pragma unroll
    for (int mi = 0; mi < 5; ++mi) {
      int cell = (h*5 + mi)*4 + quad;
      if (cell < 36) {
        int opy = cell / 6, opx = cell - opy*6;
        int wa = ((opy+1)*8 + (opx+1))*72;
        #pragma unroll
        for (int j = 0; j < 2; ++j) {
          int ch = j ? co1 : co0;
          f32x4 a = acc[mi][j];
          float v = fmaxf(fmaxf(a.x, a.y), fmaxf(a.z, a.w)) + b2[ch];
          v = v > 0.f ? v : 0.f;
          ushort_t hb = f2bf(v);
          C3h[wa + ch] = hb;
          C3l[wa + ch] = f2bf(v - bf2f(hb));
        }
      }
    }
  }
  __syncthreads();

  // ---- conv3 (64->128, K=576) MFMA ----
  {
    const ushort_t* W3 = (const ushort_t*)(ws + OFF_W3BF);
    int baseA[3];
    #pragma unroll
    for (int mt = 0; mt < 3; ++mt) {
      int m = mt*16 + col; if (m > 35) m = 35;
      int cell = m >> 2, sub = m & 3;
      int opy = cell / 3, opx = cell - opy*3;
      int y = 2*opy + (sub >> 1), xx = 2*opx + (sub & 1);
      baseA[mt] = (y*8 + xx)*72 + quad*8;
    }
    f32x4 acc[3][2];
    #pragma unroll
    for (int mt = 0; mt < 3; ++mt) { acc[mt][0] = (f32x4)0.f; acc[mt][1] = (f32x4)0.f; }
    const int co0 = wv*16 + col, co1 = co0 + 64;
    #pragma unroll
    for (int ks = 0; ks < 18; ++ks) {
      const int t9 = ks >> 1, ch0 = (ks & 1)*32;
      const int TAPOFF = ((t9/3)*8 + (t9%3))*72;
      int bidx = t9*8192 + ch0 + quad*8;
      short8 Bh0 = *(const short8*)(W3 + bidx + co0*64);
      short8 Bh1 = *(const short8*)(W3 + bidx + co1*64);
      short8 Bl0 = *(const short8*)(W3 + 73728 + bidx + co0*64);
      short8 Bl1 = *(const short8*)(W3 + 73728 + bidx + co1*64);
      #pragma unroll
      for (int mt = 0; mt < 3; ++mt) {
        int a = baseA[mt] + TAPOFF + ch0;
        short8 Ah = *(const short8*)(C3h + a);
        short8 Al = *(const short8*)(C3l + a);
        acc[mt][0] = __builtin_amdgcn_mfma_f32_16x16x32_bf16(Al, Bh0, acc[mt][0], 0, 0, 0);
        acc[mt][0] = __builtin_amdgcn_mfma_f32_16x16x32_bf16(Ah, Bl0, acc[mt][0], 0, 0, 0);
        acc[mt][0] = __builtin_amdgcn_mfma_f32_16x16x32_bf16(Ah, Bh0, acc[mt][0], 0, 0, 0);
        acc[mt][1] = __builtin_amdgcn_mfma_f32_16x16x32_bf16(Al, Bh1, acc[mt][1], 0, 0, 0);
        acc[mt][1] = __builtin_amdgcn_mfma_f32_16x16x32_bf16(Ah, Bl1, acc[mt][1], 0, 0, 0);
        acc[mt][1] = __builtin_amdgcn_mfma_f32_16x16x32_bf16(Ah, Bh1, acc[mt][1], 0, 0, 0);
      }
    }
    float* hb_ = hout + (size_t)b * 1152;
    #pragma unroll
    for (int mt = 0; mt < 3; ++mt) {
      int cell = mt*4 + quad;
      if (cell < 9) {
        #pragma unroll
        for (int j = 0; j < 2; ++j) {
          int ch = j ? co1 : co0;
          f32x4 a = acc[mt][j];
          float v = fmaxf(fmaxf(a.x, a.y), fmaxf(a.z, a.w)) + b3[ch];
          v = v > 0.f ? v : 0.f;
          hb_[ch*9 + cell] = v;
        }
      }
    }
  }
}

// ---------------- fused enc_fc + argmin: 16 samples/block (fp32 vector) ----------------
__global__ __launch_bounds__(256, 2) void vq_fc_argmin(
    const float* __restrict__ efw, const float* __restrict__ efb,
    const float* __restrict__ cb, const float* __restrict__ ws,
    const float* __restrict__ h, int* __restrict__ ids)
{
  __shared__ float HT[18432];
  __shared__ float WVs[64];
  __shared__ int   WIs[64];
  const int t = threadIdx.x;
  const int sb = blockIdx.x * 16;

  const float4* src = (const float4*)(h + (size_t)sb * 1152);
  for (int i = t; i < 4608; i += 256) ((float4*)HT)[i] = src[i];
  __syncthreads();

  const int j = t & 127, g = t >> 7;
  float acc[8];
  #pragma unroll
  for (int u = 0; u < 8; ++u) acc[u] = 0.f;
  const float* wj = efw + (size_t)j * 1152;
  for (int k4 = 0; k4 < 1152; k4 += 4) {
    float4 wvv = *(const float4*)(wj + k4);
    const float* hp = &HT[g*9216 + k4];
    #pragma unroll
    for (int u = 0; u < 8; ++u) {
      float4 hv = *(const float4*)(hp + u*1152);
      acc[u] += wvv.x*hv.x + wvv.y*hv.y + wvv.z*hv.z + wvv.w*hv.w;
    }
  }
  float bias = efb[j];
  __syncthreads();
  #pragma unroll
  for (int u = 0; u < 8; ++u) HT[(g*8 + u)*128 + j] = acc[u] + bias;
  __syncthreads();

  float bestv[16]; int besti[16];
  #pragma unroll
  for (int s = 0; s < 16; ++s) { bestv[s] = 3.4e38f; besti[s] = 0; }
  for (int c = 0; c < 4; ++c) {
    int cw = c*256 + t;
    float d[16];
    #pragma unroll
    for (int s = 0; s < 16; ++s) d[s] = 0.f;
    const float* cp = cb + (size_t)cw * 128;
    for (int k4 = 0; k4 < 128; k4 += 4) {
      float4 cv = *(const float4*)(cp + k4);
      #pragma unroll
      for (int s = 0; s < 16; ++s) {
        float4 zv = *(const float4*)(&HT[s*128 + k4]);
        d[s] += cv.x*zv.x + cv.y*zv.y + cv.z*zv.z + cv.w*zv.w;
      }
    }
    float ccv = ws[OFF_CC + cw];
    #pragma unroll
    for (int s = 0; s < 16; ++s) {
      float dist = ccv - 2.f*d[s];
      if (dist < bestv[s]) { bestv[s] = dist; besti[s] = cw; }
    }
  }
  const int lane = t & 63, wid = t >> 6;
  #pragma unroll
  for (int s = 0; s < 16; ++s) {
    float v = bestv[s]; int ii = besti[s];
    #pragma unroll
    for (int off = 32; off >= 1; off >>= 1) {
      float v2 = __shfl_xor(v, off); int i2 = __shfl_xor(ii, off);
      if (v2 < v || (v2 == v && i2 < ii)) { v = v2; ii = i2; }
    }
    if (lane == 0) { WVs[wid*16 + s] = v; WIs[wid*16 + s] = ii; }
  }
  __syncthreads();
  if (t < 16) {
    float v = WVs[t]; int ii = WIs[t];
    #pragma unroll
    for (int w2 = 1; w2 < 4; ++w2) {
      float v2 = WVs[w2*16 + t]; int i2 = WIs[w2*16 + t];
      if (v2 < v || (v2 == v && i2 < ii)) { v = v2; ii = i2; }
    }
    ids[sb + t] = ii;
  }
}

// ---------------- decode table: 2 CODEWORDS per block, 512 blocks ----------------
__global__ __launch_bounds__(256, 4) void vq_dec_table(
    const float* __restrict__ codebook, const float* __restrict__ decb,
    const float* __restrict__ d1b, const float* __restrict__ d2b, const float* __restrict__ d3b,
    const float* __restrict__ ws, float* __restrict__ table)
{
  __shared__ float DB[2304];
  __shared__ float R1[2432];
  __shared__ float R0[4736];
  __shared__ float ZQ[256];
  const int t = threadIdx.x;
  const int s0 = blockIdx.x * 2;      // codeword pair

  { int s = t >> 7, j = t & 127; ZQ[s*128 + j] = codebook[(size_t)(s0 + s)*128 + j]; }
  __syncthreads();

  #pragma unroll
  for (int p = 0; p < 5; ++p) {
    int j = t + p*256;
    if (j < 1152) {
      float a0 = decb[j], a1 = a0;
      const float* wb = ws + OFF_DWT + j;
      #pragma unroll 4
      for (int k = 0; k < 128; ++k) {
        float wv = wb[k*1152];
        a0 += wv * ZQ[k];
        a1 += wv * ZQ[128 + k];
      }
      DB[j] = a0; DB[1152 + j] = a1;
    }
  }

  for (int s = 0; s < 2; ++s) {
    __syncthreads();
    const float* F = &DB[s*1152];
    float* PS = &DB[s*1152];

    {
      int co = t & 63, g = t >> 6;
      float a9[9];
      #pragma unroll
      for (int i = 0; i < 9; ++i) a9[i] = 0.f;
      const float* wbase = ws + OFF_D1R + co;
      for (int ci = g*32; ci < g*32+32; ++ci) {
        float w[9];
        #pragma unroll
        for (int k = 0; k < 9; ++k) w[k] = wbase[(ci*9+k)*64];
        const float* fin = F + ci*9;
        #pragma unroll
        for (int ry = 0; ry < 3; ++ry) {
          float r[5];
          r[0] = 0.f; r[4] = 0.f;
          r[1] = fin[ry*3]; r[2] = fin[ry*3+1]; r[3] = fin[ry*3+2];
          #pragma unroll
          for (int y = 0; y < 3; ++y) {
            int d = ry - y + 1;
            if (d >= 0 && d < 3) {
              #pragma unroll
              for (int xx = 0; xx < 3; ++xx)
                #pragma unroll
                for (int dx = 0; dx < 3; ++dx) a9[y*3+xx] += r[xx+dx] * w[d*3+dx];
            }
          }
        }
      }
      __syncthreads();
      if (g) {
        #pragma unroll
        for (int i = 0; i < 9; ++i) R0[((g-1)*64 + co)*9 + i] = a9[i];
      }
      __syncthreads();
      if (!g) {
        float bias = d1b[co];
        #pragma unroll
        for (int i = 0; i < 9; ++i)
          a9[i] += R0[co*9 + i] + R0[(64+co)*9 + i] + R0[(128+co)*9 + i];
        #pragma unroll
        for (int yy = 0; yy < 3; ++yy)
          #pragma unroll
          for (int xx = 0; xx < 3; ++xx) {
            float v = a9[yy*3+xx] + bias; v = v > 0.f ? v : 0.f;
            int base = co*38 + (2*yy)*6 + 2*xx;
            R1[base] = v; R1[base+1] = v; R1[base+6] = v; R1[base+7] = v;
          }
      }
    }
    __syncthreads();

    {
      int co = t & 31, hh = (t >> 5) & 1, g = t >> 6;
      int sy = g >> 1, sx = g & 1;
      float a9[9];
      #pragma unroll
      for (int i = 0; i < 9; ++i) a9[i] = 0.f;
      const float* wbase = ws + OFF_D2R + co;
      for (int ci = hh*32; ci < hh*32+32; ++ci) {
        float w[9];
        #pragma unroll
        for (int k = 0; k < 9; ++k) w[k] = wbase[(ci*9+k)*32];
        const float* base = &R1[ci*38];
        #pragma unroll
        for (int wy = 0; wy < 5; ++wy) {
          int ry = sy*3 - 1 + wy;
          if (ry < 0 || ry > 5) continue;
          const float* row = base + ry*6 + sx*3;
          float r[5];
          if (sx == 0) {
            r[0] = 0.f; r[1] = row[0]; r[2] = row[1]; r[3] = row[2]; r[4] = row[3];
          } else {
            r[0] = row[-1]; r[1] = row[0]; r[2] = row[1]; r[3] = row[2]; r[4] = 0.f;
          }
          #pragma unroll
          for (int y = 0; y < 3; ++y) {
            int d = wy - 1 - y + 1;
            if (d >= 0 && d < 3) {
              #pragma unroll
              for (int xx = 0; xx < 3; ++xx)
                #pragma unroll
                for (int dx = 0; dx < 3; ++dx) a9[y*3+xx] += r[xx+dx] * w[d*3+dx];
            }
          }
        }
      }
      __syncthreads();
      if (hh) {
        #pragma unroll
        for (int i = 0; i < 9; ++i) PS[(g*32 + co)*9 + i] = a9[i];
      }
      __syncthreads();
      if (!hh) {
        float bias = d2b[co];
        #pragma unroll
        for (int i = 0; i < 9; ++i) a9[i] += PS[(g*32 + co)*9 + i];
        #pragma unroll
        for (int yy = 0; yy < 3; ++yy)
          #pragma unroll
          for (int xx = 0; xx < 3; ++xx) {
            float v = a9[yy*3+xx] + bias; v = v > 0.f ? v : 0.f;
            int rr = sy*3 + yy, cc_ = sx*3 + xx;
            int base = co*146 + (2*rr)*12 + 2*cc_;
            R0[base] = v; R0[base+1] = v; R0[base+12] = v; R0[base+13] = v;
          }
      }
    }
    __syncthreads();

    if (t < 144) {
      int yy = t / 12, xx = t - yy*12;
      const float* w3 = ws + OFF_D3R;
      float acc = d3b[0];
      for (int ci = 0; ci < 32; ++ci) {
        const float* base = &R0[ci*146];
        #pragma unroll
        for (int dy = 0; dy < 3; ++dy) {
          int ry = yy - 1 + dy;
          int ryc = ry < 0 ? 0 : (ry > 11 ? 11 : ry);
          bool rok = (ry >= 0 && ry < 12);
          #pragma unroll
          for (int dx = 0; dx < 3; ++dx) {
            int rx = xx - 1 + dx;
            int rxc = rx < 0 ? 0 : (rx > 11 ? 11 : rx);
            float v = base[ryc*12 + rxc];
            v = (rok && rx >= 0 && rx < 12) ? v : 0.f;
            acc += v * w3[ci*9 + dy*3 + dx];
          }
        }
      }
      float v = acc > 0.f ? acc : 0.f;
      float* ob = table + (size_t)(s0 + s) * 576;
      int o0 = (2*yy)*24 + 2*xx;
      ob[o0] = v; ob[o0+1] = v; ob[o0+24] = v; ob[o0+25] = v;
    }
  }
}

// ---------------- scatter: out[b] = table[ids[b]] ----------------
__global__ __launch_bounds__(256, 8) void vq_scatter(
    const float* __restrict__ table, const int* __restrict__ ids,
    float* __restrict__ out, int nvec)
{
  int idx = blockIdx.x * 256 + threadIdx.x;     // float4 index
  if (idx >= nvec) return;
  int b = idx / 144;
  int r = idx - b * 144;
  int cw = ids[b];
  ((float4*)out)[idx] = ((const float4*)(table + (size_t)cw * 576))[r];
}

extern "C" void kernel_launch(void* const* d_in, const int* in_sizes, int n_in,
                              void* d_out, int out_size, void* d_ws, size_t ws_size,
                              hipStream_t stream) {
  const float* x   = (const float*)d_in[0];
  const float* c1w = (const float*)d_in[1];
  const float* c1b = (const float*)d_in[2];
  const float* c2w = (const float*)d_in[3];
  const float* c2b = (const float*)d_in[4];
  const float* c3w = (const float*)d_in[5];
  const float* c3b = (const float*)d_in[6];
  const float* efw = (const float*)d_in[7];
  const float* efb = (const float*)d_in[8];
  const float* cb  = (const float*)d_in[9];
  const float* dfw = (const float*)d_in[10];
  const float* dfb = (const float*)d_in[11];
  const float* dw1 = (const float*)d_in[12];
  const float* db1 = (const float*)d_in[13];
  const float* dw2 = (const float*)d_in[14];
  const float* db2 = (const float*)d_in[15];
  const float* dw3 = (const float*)d_in[16];
  const float* db3 = (const float*)d_in[17];
  float* ws = (float*)d_ws;
  float* h     = ws + OFF_H;
  float* table = ws + OFF_TABLE;     // overlays h (h dead after fc_argmin)
  int*   ids   = (int*)(ws + OFF_IDSN);
  float* outp = (float*)d_out;
  int B = in_sizes[0] / 576;

  vq_prep<<<(WS_WEIGHTS + 255) / 256, 256, 0, stream>>>(c1w, c2w, c3w, efw, cb, dfw, dw1, dw2, dw3, ws);
  vq_prep2<<<(92160 + 255) / 256, 256, 0, stream>>>(c2w, c3w, ws);
  vq_enc<<<B, 256, 0, stream>>>(x, c1b, c2b, c3b, ws, h);
  vq_fc_argmin<<<B/16, 256, 0, stream>>>(efw, efb, cb, ws, h, ids);
  vq_dec_table<<<512, 256, 0, stream>>>(cb, dfb, db1, db2, db3, ws, table);
  int nvec = B * 144;
  vq_scatter<<<(nvec + 255) / 256, 256, 0, stream>>>(table, ids, outp, nvec);
}